// Round 5
// baseline (532.545 us; speedup 1.0000x reference)
//
#include <hip/hip_runtime.h>

#define N_NODES 50000
#define N_EDGES 300000
#define DIM 256
#define HID 128
#define INP 64
#define BATCH 4096
#define SEQ 50
#define SCAN_BLOCKS 196   // ceil(50000/256)

typedef float f32x2 __attribute__((ext_vector_type(2)));
typedef float f32x4 __attribute__((ext_vector_type(4)));
typedef __bf16 bf16x2 __attribute__((ext_vector_type(2)));
typedef __bf16 bf16x8 __attribute__((ext_vector_type(8)));

// fast activations: v_rcp_f32 instead of IEEE divide (~1 ulp, inf-safe)
__device__ __forceinline__ float sigmoidf_(float x) {
    return __builtin_amdgcn_rcpf(1.0f + __expf(-x));
}
__device__ __forceinline__ float tanhf_(float x) {
    return 1.0f - 2.0f * __builtin_amdgcn_rcpf(1.0f + __expf(2.0f * x));
}

// ---------------- GCN: counting sort by head ----------------

__global__ void k_hist(const int* __restrict__ head, int* __restrict__ deg) {
    int e = blockIdx.x * 256 + threadIdx.x;
    if (e < N_EDGES) atomicAdd(&deg[head[e]], 1);
}

__global__ void k_bsum(const int* __restrict__ deg, int* __restrict__ bsum) {
    __shared__ int red[256];
    int n = blockIdx.x * 256 + threadIdx.x;
    red[threadIdx.x] = (n < N_NODES) ? deg[n] : 0;
    __syncthreads();
    for (int st = 128; st > 0; st >>= 1) {
        if (threadIdx.x < st) red[threadIdx.x] += red[threadIdx.x + st];
        __syncthreads();
    }
    if (threadIdx.x == 0) bsum[blockIdx.x] = red[0];
}

__global__ void k_scanb(const int* __restrict__ bsum, int* __restrict__ boff) {
    __shared__ int s[256];
    int i = threadIdx.x;
    int v = (i < SCAN_BLOCKS) ? bsum[i] : 0;
    s[i] = v;
    __syncthreads();
    for (int st = 1; st < 256; st <<= 1) {
        int add = (i >= st) ? s[i - st] : 0;
        __syncthreads();
        s[i] += add;
        __syncthreads();
    }
    boff[i] = s[i] - v;   // exclusive
}

__global__ void k_scan2(const int* __restrict__ deg, const int* __restrict__ boff,
                        int* __restrict__ offsets, int* __restrict__ cursor) {
    __shared__ int s[256];
    int i = threadIdx.x;
    int n = blockIdx.x * 256 + i;
    int v = (n < N_NODES) ? deg[n] : 0;
    s[i] = v;
    __syncthreads();
    for (int st = 1; st < 256; st <<= 1) {
        int add = (i >= st) ? s[i - st] : 0;
        __syncthreads();
        s[i] += add;
        __syncthreads();
    }
    if (n < N_NODES) {
        int off = boff[blockIdx.x] + s[i] - v;
        offsets[n] = off;
        cursor[n] = off;
    }
    if (n == 0) offsets[N_NODES] = N_EDGES;
}

__global__ void k_place(const int* __restrict__ head, const int* __restrict__ tail,
                        const int* __restrict__ etype, int* __restrict__ cursor,
                        int* __restrict__ sorted) {
    int e = blockIdx.x * 256 + threadIdx.x;
    if (e >= N_EDGES) return;
    int h = head[e];
    int pos = atomicAdd(&cursor[h], 1);
    sorted[pos] = tail[e] | (etype[e] << 16);   // tail<65536, etype<32
}

// Hop 1: one wave per node; lane holds dims [4*lane, 4*lane+4). No atomics.
// relw read directly from global (32 KB, L1-resident) -> no LDS, high occupancy.
__global__ void k_gather(const int* __restrict__ offsets, const int* __restrict__ sorted,
                         const float* __restrict__ relw, const float* __restrict__ src,
                         float* __restrict__ dst) {
    int tid = threadIdx.x;
    int w = tid >> 6, lane = tid & 63;
    int n = blockIdx.x * 4 + w;
    if (n >= N_NODES) return;
    int s = offsets[n], e = offsets[n + 1];
    f32x4 acc0 = (f32x4){0.f, 0.f, 0.f, 0.f};
    f32x4 acc1 = (f32x4){0.f, 0.f, 0.f, 0.f};
    f32x4 acc2 = (f32x4){0.f, 0.f, 0.f, 0.f};
    f32x4 acc3 = (f32x4){0.f, 0.f, 0.f, 0.f};
    int j = s;
    for (; j + 4 <= e; j += 4) {
        int p0 = sorted[j], p1 = sorted[j + 1], p2 = sorted[j + 2], p3 = sorted[j + 3];
        f32x4 v0 = *(const f32x4*)(src + (size_t)(p0 & 0xFFFF) * DIM + lane * 4);
        f32x4 v1 = *(const f32x4*)(src + (size_t)(p1 & 0xFFFF) * DIM + lane * 4);
        f32x4 v2 = *(const f32x4*)(src + (size_t)(p2 & 0xFFFF) * DIM + lane * 4);
        f32x4 v3 = *(const f32x4*)(src + (size_t)(p3 & 0xFFFF) * DIM + lane * 4);
        acc0 += v0 * *(const f32x4*)(relw + (p0 >> 16) * DIM + lane * 4);
        acc1 += v1 * *(const f32x4*)(relw + (p1 >> 16) * DIM + lane * 4);
        acc2 += v2 * *(const f32x4*)(relw + (p2 >> 16) * DIM + lane * 4);
        acc3 += v3 * *(const f32x4*)(relw + (p3 >> 16) * DIM + lane * 4);
    }
    for (; j < e; j++) {
        int p0 = sorted[j];
        f32x4 v0 = *(const f32x4*)(src + (size_t)(p0 & 0xFFFF) * DIM + lane * 4);
        acc0 += v0 * *(const f32x4*)(relw + (p0 >> 16) * DIM + lane * 4);
    }
    acc0 = (acc0 + acc1) + (acc2 + acc3);
    float inv = 1.0f / fmaxf((float)(e - s), 1.0f);
    *(f32x4*)(dst + (size_t)n * DIM + lane * 4) = acc0 * inv;
}

// Hop 2 only at batch nodes, fused with struct = (emb + out1 + out2)/3.
__global__ void k_gather2(const int* __restrict__ nidx, const int* __restrict__ offsets,
                          const int* __restrict__ sorted, const float* __restrict__ relw,
                          const float* __restrict__ out1, const float* __restrict__ emb,
                          float* __restrict__ structb) {
    int tid = threadIdx.x;
    int w = tid >> 6, lane = tid & 63;
    int b = blockIdx.x * 4 + w;          // grid = 1024 blocks, exact
    int n = nidx[b];
    int s = offsets[n], e = offsets[n + 1];
    f32x4 acc0 = (f32x4){0.f, 0.f, 0.f, 0.f};
    f32x4 acc1 = (f32x4){0.f, 0.f, 0.f, 0.f};
    f32x4 acc2 = (f32x4){0.f, 0.f, 0.f, 0.f};
    f32x4 acc3 = (f32x4){0.f, 0.f, 0.f, 0.f};
    int j = s;
    for (; j + 4 <= e; j += 4) {
        int p0 = sorted[j], p1 = sorted[j + 1], p2 = sorted[j + 2], p3 = sorted[j + 3];
        f32x4 v0 = *(const f32x4*)(out1 + (size_t)(p0 & 0xFFFF) * DIM + lane * 4);
        f32x4 v1 = *(const f32x4*)(out1 + (size_t)(p1 & 0xFFFF) * DIM + lane * 4);
        f32x4 v2 = *(const f32x4*)(out1 + (size_t)(p2 & 0xFFFF) * DIM + lane * 4);
        f32x4 v3 = *(const f32x4*)(out1 + (size_t)(p3 & 0xFFFF) * DIM + lane * 4);
        acc0 += v0 * *(const f32x4*)(relw + (p0 >> 16) * DIM + lane * 4);
        acc1 += v1 * *(const f32x4*)(relw + (p1 >> 16) * DIM + lane * 4);
        acc2 += v2 * *(const f32x4*)(relw + (p2 >> 16) * DIM + lane * 4);
        acc3 += v3 * *(const f32x4*)(relw + (p3 >> 16) * DIM + lane * 4);
    }
    for (; j < e; j++) {
        int p0 = sorted[j];
        f32x4 v0 = *(const f32x4*)(out1 + (size_t)(p0 & 0xFFFF) * DIM + lane * 4);
        acc0 += v0 * *(const f32x4*)(relw + (p0 >> 16) * DIM + lane * 4);
    }
    acc0 = (acc0 + acc1) + (acc2 + acc3);
    float inv = 1.0f / fmaxf((float)(e - s), 1.0f);
    f32x4 o2 = acc0 * inv;
    f32x4 e0 = *(const f32x4*)(emb + (size_t)n * DIM + lane * 4);
    f32x4 o1 = *(const f32x4*)(out1 + (size_t)n * DIM + lane * 4);
    *(f32x4*)(structb + (size_t)b * DIM + lane * 4) = (e0 + o1 + o2) * (1.0f / 3.0f);
}

// ---------------- BiLSTM ----------------
// Pack W = [Wih | Whh] (bf16, K=192) into MFMA B-fragment order, 512-elem frags:
// per dir: frag = (w*4+g)*6+kc  (w=wave 0..7, g=gate 0..3, kc=0..5)
// within-frag = lane*8+j ; value = W[n][k],
//   n = g*128 + w*16 + (lane&15),  k = kc*32 + (lane>>4)*8 + j
__global__ void k_w2frag(const float* __restrict__ Wih_f, const float* __restrict__ Whh_f,
                         const float* __restrict__ Wih_b, const float* __restrict__ Whh_b,
                         __bf16* __restrict__ w2) {
    int idx = blockIdx.x * 256 + threadIdx.x;   // 2 * 192 * 512 = 196608
    int dir = idx / 98304;
    int rem = idx % 98304;
    int frag = rem >> 9;        // 0..191
    int within = rem & 511;
    int lane = within >> 3, j = within & 7;
    int kc = frag % 6;
    int wg = frag / 6;          // 0..31
    int g = wg & 3, w = wg >> 2;
    int n = g * 128 + w * 16 + (lane & 15);
    int k = kc * 32 + (lane >> 4) * 8 + j;
    const float* Wih = dir ? Wih_b : Wih_f;
    const float* Whh = dir ? Whh_b : Whh_f;
    float v = (k < 64) ? Wih[n * 64 + k] : Whh[n * 128 + (k - 64)];
    w2[idx] = (__bf16)v;
}

// Block = 8 waves (512 thr), M=16 samples, one direction, all 50 steps.
// Wave w owns hidden cols [w*16, w*16+16) for ALL four gates.
// kc=1..5 weight frags in VGPRs (20 frags = 80 regs); kc=0 frags staged in LDS.
// Grid 512 blocks -> 2 blocks/CU (needs VGPR<=128 via launch_bounds(512,4));
// two independent blocks per CU overlap MFMA phase with cell-VALU phase.
__launch_bounds__(512, 4)
__global__ void k_lstm(const float* __restrict__ ts, const __bf16* __restrict__ w2frag,
                       const float* __restrict__ b_f, const float* __restrict__ b_b,
                       float* __restrict__ temporal) {
    int dir = blockIdx.y;
    int btile = blockIdx.x;    // 0..255
    int tid = threadIdx.x;
    int w = tid >> 6;          // wave 0..7
    int lane = tid & 63;
    int col = lane & 15, quad = lane >> 4;

    __shared__ __align__(16) __bf16 A[16][200];      // [m][k], K=192 pad 200 (400B rows, 16B-aligned)
    __shared__ __align__(16) __bf16 K0[8 * 4 * 512]; // kc=0 weight frags, per (wave,gate)

    // zero h region (k = 64..191): 16*128 elems
    for (int i = tid; i < 16 * 128; i += 512) {
        A[i >> 7][64 + (i & 127)] = (__bf16)0.0f;
    }

    const float* bias = dir ? b_b : b_f;
    float bv[4];
#pragma unroll
    for (int g = 0; g < 4; g++) {
        bv[g] = bias[g * 128 + w * 16 + col];
    }

    const __bf16* wbase = w2frag + (size_t)dir * 98304 + (size_t)w * 12288;
    // kc=0 frags -> LDS (once)
#pragma unroll
    for (int g = 0; g < 4; g++) {
        *(bf16x8*)&K0[((w * 4 + g) << 9) + lane * 8] =
            *(const bf16x8*)(wbase + ((g * 6 + 0) << 9) + lane * 8);
    }
    // kc=1..5 frags -> VGPRs (20 frags = 80 VGPRs)
    bf16x8 wreg[20];
#pragma unroll
    for (int g = 0; g < 4; g++) {
#pragma unroll
        for (int kc = 1; kc < 6; kc++) {
            wreg[g * 5 + (kc - 1)] = *(const bf16x8*)(wbase + ((g * 6 + kc) << 9) + lane * 8);
        }
    }

    // x staging: thread -> row sm = tid>>5 (0..15), col pair sc = (tid&31)*2
    int sm = tid >> 5, sc = (tid & 31) * 2;
    const float* xbase = ts + ((size_t)(btile * 16 + sm) * SEQ) * INP + sc;
    f32x2 xpre = *(const f32x2*)(xbase + (size_t)(dir ? (SEQ - 1) : 0) * INP);

    f32x4 c_reg = (f32x4){0.f, 0.f, 0.f, 0.f};
    f32x4 hsum  = (f32x4){0.f, 0.f, 0.f, 0.f};
    __syncthreads();

    for (int t = 0; t < SEQ; t++) {
        // write prefetched x_t to LDS (bf16x2 = 4B store)
        {
            bf16x2 xv;
            xv[0] = (__bf16)xpre.x; xv[1] = (__bf16)xpre.y;
            *(bf16x2*)&A[sm][sc] = xv;
        }
        if (t + 1 < SEQ) {
            int tt = dir ? (SEQ - 2 - t) : (t + 1);
            xpre = *(const f32x2*)(xbase + (size_t)tt * INP);
        }
        __syncthreads();

        f32x4 acc[4];
#pragma unroll
        for (int g = 0; g < 4; g++) {
            acc[g] = (f32x4){bv[g], bv[g], bv[g], bv[g]};
        }
#pragma unroll
        for (int kc = 1; kc < 6; kc++) {
            bf16x8 a0 = *(const bf16x8*)&A[col][kc * 32 + quad * 8];
#pragma unroll
            for (int g = 0; g < 4; g++) {
                acc[g] = __builtin_amdgcn_mfma_f32_16x16x32_bf16(a0, wreg[g * 5 + (kc - 1)], acc[g], 0, 0, 0);
            }
        }
        {
            bf16x8 a0 = *(const bf16x8*)&A[col][quad * 8];
#pragma unroll
            for (int g = 0; g < 4; g++) {
                bf16x8 k0 = *(const bf16x8*)&K0[((w * 4 + g) << 9) + lane * 8];
                acc[g] = __builtin_amdgcn_mfma_f32_16x16x32_bf16(a0, k0, acc[g], 0, 0, 0);
            }
        }
        __syncthreads();   // all A reads done before h_t overwrite

        // cell update: lane owns (b=quad*4+r, j=w*16+col); i/f/g/o same lane+reg
#pragma unroll
        for (int r = 0; r < 4; r++) {
            float iv = acc[0][r];
            float fv = acc[1][r];
            float gv = acc[2][r];
            float ov = acc[3][r];
            float c = sigmoidf_(fv) * c_reg[r] + sigmoidf_(iv) * tanhf_(gv);
            float h = sigmoidf_(ov) * tanhf_(c);
            c_reg[r] = c;
            hsum[r] += h;
            A[quad * 4 + r][64 + w * 16 + col] = (__bf16)h;
        }
    }

    // temporal[b][dir*128 + j] = mean over t of h
#pragma unroll
    for (int r = 0; r < 4; r++) {
        int b = btile * 16 + quad * 4 + r;
        int j = w * 16 + col;
        temporal[(size_t)b * 256 + dir * 128 + j] = hsum[r] * (1.0f / SEQ);
    }
}

// ---------------- Head ----------------

__global__ void k_gate(const float* __restrict__ structb, const float* __restrict__ temporal,
                       const float* __restrict__ gate_W, const float* __restrict__ gate_b,
                       float* __restrict__ merged) {
    int bt = blockIdx.x;      // 256 blocks x 16 samples
    int n = threadIdx.x;      // output unit
    __shared__ __align__(16) float cat[16][512];
    for (int i = n; i < 16 * 512; i += 256) {
        int bb = i >> 9, k = i & 511;
        int b = bt * 16 + bb;
        cat[bb][k] = (k < 256) ? structb[(size_t)b * 256 + k]
                               : temporal[(size_t)b * 256 + (k - 256)];
    }
    __syncthreads();
    float acc[16];
#pragma unroll
    for (int bb = 0; bb < 16; bb++) acc[bb] = gate_b[n];
    const float* wrow = gate_W + (size_t)n * 512;
    for (int k4 = 0; k4 < 512; k4 += 4) {
        f32x4 wv = *(const f32x4*)(wrow + k4);
#pragma unroll
        for (int bb = 0; bb < 16; bb++) {
            f32x4 cv = *(const f32x4*)&cat[bb][k4];
            acc[bb] += cv.x * wv.x + cv.y * wv.y + cv.z * wv.z + cv.w * wv.w;
        }
    }
    int b0 = bt * 16;
#pragma unroll
    for (int bb = 0; bb < 16; bb++) {
        float g = sigmoidf_(acc[bb]);
        float s = structb[(size_t)(b0 + bb) * 256 + n];
        float tm = temporal[(size_t)(b0 + bb) * 256 + n];
        merged[(size_t)(b0 + bb) * 256 + n] = g * s + (1.0f - g) * tm;
    }
}

__global__ void k_risk1(const float* __restrict__ merged, const float* __restrict__ W1,
                        const float* __restrict__ b1, float* __restrict__ t1) {
    int bt = blockIdx.x;      // 256 blocks x 16 samples
    int n = threadIdx.x;
    __shared__ __align__(16) float mt[16][256];
    for (int i = n; i < 16 * 256; i += 256) {
        int bb = i >> 8, k = i & 255;
        mt[bb][k] = merged[(size_t)(bt * 16 + bb) * 256 + k];
    }
    __syncthreads();
    float acc[16];
#pragma unroll
    for (int bb = 0; bb < 16; bb++) acc[bb] = b1[n];
    const float* wrow = W1 + (size_t)n * 256;
    for (int k4 = 0; k4 < 256; k4 += 4) {
        f32x4 wv = *(const f32x4*)(wrow + k4);
#pragma unroll
        for (int bb = 0; bb < 16; bb++) {
            f32x4 cv = *(const f32x4*)&mt[bb][k4];
            acc[bb] += cv.x * wv.x + cv.y * wv.y + cv.z * wv.z + cv.w * wv.w;
        }
    }
#pragma unroll
    for (int bb = 0; bb < 16; bb++) {
        t1[(size_t)(bt * 16 + bb) * 256 + n] = tanhf_(acc[bb]);
    }
}

// risk.sum(-1) collapses: sum_n(t1@W2^T + b2) = t1 . colsum(W2) + sum(b2)
__global__ void k_w2sum(const float* __restrict__ W2, const float* __restrict__ b2,
                        float* __restrict__ w2s) {
    int k = threadIdx.x;
    float s = 0.0f;
    for (int n = 0; n < 256; n++) s += W2[(size_t)n * 256 + k];
    w2s[k] = s;
    __shared__ float red[256];
    red[k] = b2[k];
    __syncthreads();
    for (int st = 128; st > 0; st >>= 1) {
        if (k < st) red[k] += red[k + st];
        __syncthreads();
    }
    if (k == 0) w2s[256] = red[0];
}

__global__ void k_final(const float* __restrict__ t1, const float* __restrict__ w2s,
                        float* __restrict__ out) {
    int b = (blockIdx.x * 256 + threadIdx.x) >> 6;   // one wave per sample
    int lane = threadIdx.x & 63;
    const float* row = t1 + (size_t)b * 256;
    float s = 0.0f;
#pragma unroll
    for (int q = 0; q < 4; q++) s += row[lane + q * 64] * w2s[lane + q * 64];
#pragma unroll
    for (int off = 32; off > 0; off >>= 1) s += __shfl_down(s, off, 64);
    if (lane == 0) out[b] = sigmoidf_(s + w2s[256]);
}

// ---------------- launch ----------------

extern "C" void kernel_launch(void* const* d_in, const int* in_sizes, int n_in,
                              void* d_out, int out_size, void* d_ws, size_t ws_size,
                              hipStream_t stream) {
    const float* ts       = (const float*)d_in[0];
    const float* node_emb = (const float*)d_in[1];
    const float* rel_w    = (const float*)d_in[2];
    const float* gate_W   = (const float*)d_in[3];
    const float* gate_b   = (const float*)d_in[4];
    const float* risk_W1  = (const float*)d_in[5];
    const float* risk_b1  = (const float*)d_in[6];
    const float* risk_W2  = (const float*)d_in[7];
    const float* risk_b2  = (const float*)d_in[8];
    const float* Wih_f    = (const float*)d_in[9];
    const float* Whh_f    = (const float*)d_in[10];
    const float* b_f      = (const float*)d_in[11];
    const float* Wih_b    = (const float*)d_in[12];
    const float* Whh_b    = (const float*)d_in[13];
    const float* b_b      = (const float*)d_in[14];
    const int* edge_index = (const int*)d_in[15];
    const int* edge_type  = (const int*)d_in[16];
    const int* node_idx   = (const int*)d_in[17];
    const int* head = edge_index;
    const int* tail = edge_index + N_EDGES;
    float* out = (float*)d_out;

    char* ws = (char*)d_ws;
    const size_t o_deg      = 0;                            // 50000 int
    const size_t o_deg_end  = 200704;
    const size_t o_bsum     = o_deg_end;                    // 196 int -> pad 1024
    const size_t o_boff     = o_bsum + 1024;                // 256 int
    const size_t o_offsets  = o_boff + 1024;                // 50001 int -> pad 200960
    const size_t o_cursor   = o_offsets + 200960;           // 50000 int
    const size_t o_sorted   = o_cursor + 200704;            // 300000 int
    const size_t o_out1     = o_sorted + 1200128;           // 51,200,000 B
    const size_t o_temporal = o_out1 + 51200000;            // 4 MB
    const size_t o_struct   = o_temporal + 4194304;
    const size_t o_merged   = o_struct + 4194304;
    const size_t o_t1       = o_merged + 4194304;
    const size_t o_w2s      = o_t1 + 4194304;
    const size_t o_w2frag   = o_w2s + 2048;                 // 393216 B

    int*    deg      = (int*)(ws + o_deg);
    int*    bsum     = (int*)(ws + o_bsum);
    int*    boff     = (int*)(ws + o_boff);
    int*    offsets  = (int*)(ws + o_offsets);
    int*    cursor   = (int*)(ws + o_cursor);
    int*    sorted   = (int*)(ws + o_sorted);
    float*  out1     = (float*)(ws + o_out1);
    float*  temporal = (float*)(ws + o_temporal);
    float*  structb  = (float*)(ws + o_struct);
    float*  merged   = (float*)(ws + o_merged);
    float*  t1       = (float*)(ws + o_t1);
    float*  w2s      = (float*)(ws + o_w2s);
    __bf16* w2frag   = (__bf16*)(ws + o_w2frag);

    hipMemsetAsync(deg, 0, N_NODES * sizeof(int), stream);

    k_w2frag<<<768, 256, 0, stream>>>(Wih_f, Whh_f, Wih_b, Whh_b, w2frag);
    k_hist<<<(N_EDGES + 255) / 256, 256, 0, stream>>>(head, deg);
    k_bsum<<<SCAN_BLOCKS, 256, 0, stream>>>(deg, bsum);
    k_scanb<<<1, 256, 0, stream>>>(bsum, boff);
    k_scan2<<<SCAN_BLOCKS, 256, 0, stream>>>(deg, boff, offsets, cursor);
    k_place<<<(N_EDGES + 255) / 256, 256, 0, stream>>>(head, tail, edge_type, cursor, sorted);
    k_gather<<<(N_NODES + 3) / 4, 256, 0, stream>>>(offsets, sorted, rel_w, node_emb, out1);
    k_lstm<<<dim3(BATCH / 16, 2), 512, 0, stream>>>(ts, w2frag, b_f, b_b, temporal);
    k_gather2<<<BATCH / 4, 256, 0, stream>>>(node_idx, offsets, sorted, rel_w, out1, node_emb, structb);
    k_gate<<<BATCH / 16, 256, 0, stream>>>(structb, temporal, gate_W, gate_b, merged);
    k_risk1<<<BATCH / 16, 256, 0, stream>>>(merged, risk_W1, risk_b1, t1);
    k_w2sum<<<1, 256, 0, stream>>>(risk_W2, risk_b2, w2s);
    k_final<<<BATCH / 4, 256, 0, stream>>>(t1, w2s, out);
}

// Round 6
// 357.718 us; speedup vs baseline: 1.4887x; 1.4887x over previous
//
#include <hip/hip_runtime.h>

#define N_NODES 50000
#define N_EDGES 300000
#define DIM 256
#define HID 128
#define INP 64
#define BATCH 4096
#define SEQ 50
#define SCAN_BLOCKS 196   // ceil(50000/256)

typedef float f32x4 __attribute__((ext_vector_type(4)));
typedef __bf16 bf16x4 __attribute__((ext_vector_type(4)));
typedef __bf16 bf16x8 __attribute__((ext_vector_type(8)));

// fast activations: v_rcp_f32 instead of IEEE divide (~1 ulp, inf-safe)
__device__ __forceinline__ float sigmoidf_(float x) {
    return __builtin_amdgcn_rcpf(1.0f + __expf(-x));
}
__device__ __forceinline__ float tanhf_(float x) {
    return 1.0f - 2.0f * __builtin_amdgcn_rcpf(1.0f + __expf(2.0f * x));
}

// ---------------- GCN: counting sort by head ----------------

__global__ void k_hist(const int* __restrict__ head, int* __restrict__ deg) {
    int e = blockIdx.x * 256 + threadIdx.x;
    if (e < N_EDGES) atomicAdd(&deg[head[e]], 1);
}

__global__ void k_bsum(const int* __restrict__ deg, int* __restrict__ bsum) {
    __shared__ int red[256];
    int n = blockIdx.x * 256 + threadIdx.x;
    red[threadIdx.x] = (n < N_NODES) ? deg[n] : 0;
    __syncthreads();
    for (int st = 128; st > 0; st >>= 1) {
        if (threadIdx.x < st) red[threadIdx.x] += red[threadIdx.x + st];
        __syncthreads();
    }
    if (threadIdx.x == 0) bsum[blockIdx.x] = red[0];
}

__global__ void k_scanb(const int* __restrict__ bsum, int* __restrict__ boff) {
    __shared__ int s[256];
    int i = threadIdx.x;
    int v = (i < SCAN_BLOCKS) ? bsum[i] : 0;
    s[i] = v;
    __syncthreads();
    for (int st = 1; st < 256; st <<= 1) {
        int add = (i >= st) ? s[i - st] : 0;
        __syncthreads();
        s[i] += add;
        __syncthreads();
    }
    boff[i] = s[i] - v;   // exclusive
}

__global__ void k_scan2(const int* __restrict__ deg, const int* __restrict__ boff,
                        int* __restrict__ offsets, int* __restrict__ cursor) {
    __shared__ int s[256];
    int i = threadIdx.x;
    int n = blockIdx.x * 256 + i;
    int v = (n < N_NODES) ? deg[n] : 0;
    s[i] = v;
    __syncthreads();
    for (int st = 1; st < 256; st <<= 1) {
        int add = (i >= st) ? s[i - st] : 0;
        __syncthreads();
        s[i] += add;
        __syncthreads();
    }
    if (n < N_NODES) {
        int off = boff[blockIdx.x] + s[i] - v;
        offsets[n] = off;
        cursor[n] = off;
    }
    if (n == 0) offsets[N_NODES] = N_EDGES;
}

__global__ void k_place(const int* __restrict__ head, const int* __restrict__ tail,
                        const int* __restrict__ etype, int* __restrict__ cursor,
                        int* __restrict__ sorted) {
    int e = blockIdx.x * 256 + threadIdx.x;
    if (e >= N_EDGES) return;
    int h = head[e];
    int pos = atomicAdd(&cursor[h], 1);
    sorted[pos] = tail[e] | (etype[e] << 16);   // tail<65536, etype<32
}

// Hop 1: one wave per node; lane holds dims [4*lane, 4*lane+4). No atomics.
// relw read directly from global (32 KB, L1-resident) -> no LDS, high occupancy.
__global__ void k_gather(const int* __restrict__ offsets, const int* __restrict__ sorted,
                         const float* __restrict__ relw, const float* __restrict__ src,
                         float* __restrict__ dst) {
    int tid = threadIdx.x;
    int w = tid >> 6, lane = tid & 63;
    int n = blockIdx.x * 4 + w;
    if (n >= N_NODES) return;
    int s = offsets[n], e = offsets[n + 1];
    f32x4 acc0 = (f32x4){0.f, 0.f, 0.f, 0.f};
    f32x4 acc1 = (f32x4){0.f, 0.f, 0.f, 0.f};
    f32x4 acc2 = (f32x4){0.f, 0.f, 0.f, 0.f};
    f32x4 acc3 = (f32x4){0.f, 0.f, 0.f, 0.f};
    int j = s;
    for (; j + 4 <= e; j += 4) {
        int p0 = sorted[j], p1 = sorted[j + 1], p2 = sorted[j + 2], p3 = sorted[j + 3];
        f32x4 v0 = *(const f32x4*)(src + (size_t)(p0 & 0xFFFF) * DIM + lane * 4);
        f32x4 v1 = *(const f32x4*)(src + (size_t)(p1 & 0xFFFF) * DIM + lane * 4);
        f32x4 v2 = *(const f32x4*)(src + (size_t)(p2 & 0xFFFF) * DIM + lane * 4);
        f32x4 v3 = *(const f32x4*)(src + (size_t)(p3 & 0xFFFF) * DIM + lane * 4);
        acc0 += v0 * *(const f32x4*)(relw + (p0 >> 16) * DIM + lane * 4);
        acc1 += v1 * *(const f32x4*)(relw + (p1 >> 16) * DIM + lane * 4);
        acc2 += v2 * *(const f32x4*)(relw + (p2 >> 16) * DIM + lane * 4);
        acc3 += v3 * *(const f32x4*)(relw + (p3 >> 16) * DIM + lane * 4);
    }
    for (; j < e; j++) {
        int p0 = sorted[j];
        f32x4 v0 = *(const f32x4*)(src + (size_t)(p0 & 0xFFFF) * DIM + lane * 4);
        acc0 += v0 * *(const f32x4*)(relw + (p0 >> 16) * DIM + lane * 4);
    }
    acc0 = (acc0 + acc1) + (acc2 + acc3);
    float inv = 1.0f / fmaxf((float)(e - s), 1.0f);
    *(f32x4*)(dst + (size_t)n * DIM + lane * 4) = acc0 * inv;
}

// Hop 2 only at batch nodes, fused with struct = (emb + out1 + out2)/3.
__global__ void k_gather2(const int* __restrict__ nidx, const int* __restrict__ offsets,
                          const int* __restrict__ sorted, const float* __restrict__ relw,
                          const float* __restrict__ out1, const float* __restrict__ emb,
                          float* __restrict__ structb) {
    int tid = threadIdx.x;
    int w = tid >> 6, lane = tid & 63;
    int b = blockIdx.x * 4 + w;          // grid = 1024 blocks, exact
    int n = nidx[b];
    int s = offsets[n], e = offsets[n + 1];
    f32x4 acc0 = (f32x4){0.f, 0.f, 0.f, 0.f};
    f32x4 acc1 = (f32x4){0.f, 0.f, 0.f, 0.f};
    f32x4 acc2 = (f32x4){0.f, 0.f, 0.f, 0.f};
    f32x4 acc3 = (f32x4){0.f, 0.f, 0.f, 0.f};
    int j = s;
    for (; j + 4 <= e; j += 4) {
        int p0 = sorted[j], p1 = sorted[j + 1], p2 = sorted[j + 2], p3 = sorted[j + 3];
        f32x4 v0 = *(const f32x4*)(out1 + (size_t)(p0 & 0xFFFF) * DIM + lane * 4);
        f32x4 v1 = *(const f32x4*)(out1 + (size_t)(p1 & 0xFFFF) * DIM + lane * 4);
        f32x4 v2 = *(const f32x4*)(out1 + (size_t)(p2 & 0xFFFF) * DIM + lane * 4);
        f32x4 v3 = *(const f32x4*)(out1 + (size_t)(p3 & 0xFFFF) * DIM + lane * 4);
        acc0 += v0 * *(const f32x4*)(relw + (p0 >> 16) * DIM + lane * 4);
        acc1 += v1 * *(const f32x4*)(relw + (p1 >> 16) * DIM + lane * 4);
        acc2 += v2 * *(const f32x4*)(relw + (p2 >> 16) * DIM + lane * 4);
        acc3 += v3 * *(const f32x4*)(relw + (p3 >> 16) * DIM + lane * 4);
    }
    for (; j < e; j++) {
        int p0 = sorted[j];
        f32x4 v0 = *(const f32x4*)(out1 + (size_t)(p0 & 0xFFFF) * DIM + lane * 4);
        acc0 += v0 * *(const f32x4*)(relw + (p0 >> 16) * DIM + lane * 4);
    }
    acc0 = (acc0 + acc1) + (acc2 + acc3);
    float inv = 1.0f / fmaxf((float)(e - s), 1.0f);
    f32x4 o2 = acc0 * inv;
    f32x4 e0 = *(const f32x4*)(emb + (size_t)n * DIM + lane * 4);
    f32x4 o1 = *(const f32x4*)(out1 + (size_t)n * DIM + lane * 4);
    *(f32x4*)(structb + (size_t)b * DIM + lane * 4) = (e0 + o1 + o2) * (1.0f / 3.0f);
}

// ---------------- BiLSTM ----------------
// Pack W = [Wih | Whh] (bf16, K=192) into MFMA B-fragment order, 512-elem frags:
// per dir: frag = (w*4+g)*6+kc  (w=wave 0..7, g=gate 0..3, kc=0..5)
// within-frag = lane*8+j ; value = W[n][k],
//   n = g*128 + w*16 + (lane&15),  k = kc*32 + (lane>>4)*8 + j
__global__ void k_w2frag(const float* __restrict__ Wih_f, const float* __restrict__ Whh_f,
                         const float* __restrict__ Wih_b, const float* __restrict__ Whh_b,
                         __bf16* __restrict__ w2) {
    int idx = blockIdx.x * 256 + threadIdx.x;   // 2 * 192 * 512 = 196608
    int dir = idx / 98304;
    int rem = idx % 98304;
    int frag = rem >> 9;        // 0..191
    int within = rem & 511;
    int lane = within >> 3, j = within & 7;
    int kc = frag % 6;
    int wg = frag / 6;          // 0..31
    int g = wg & 3, w = wg >> 2;
    int n = g * 128 + w * 16 + (lane & 15);
    int k = kc * 32 + (lane >> 4) * 8 + j;
    const float* Wih = dir ? Wih_b : Wih_f;
    const float* Whh = dir ? Whh_b : Whh_f;
    float v = (k < 64) ? Wih[n * 64 + k] : Whh[n * 128 + (k - 64)];
    w2[idx] = (__bf16)v;
}

// Generic packer: W[N][K] fp32 -> bf16 MFMA B-frags.
// frag T*Kc+kc (T=n-tile of 16, Kc=K/32), within = lane*8+j:
//   n = T*16+(lane&15), k = kc*32+(lane>>4)*8+j
__global__ void k_packw(const float* __restrict__ W, __bf16* __restrict__ dst,
                        int K, int total) {
    int idx = blockIdx.x * 256 + threadIdx.x;
    if (idx >= total) return;
    int frag = idx >> 9, within = idx & 511;
    int lane = within >> 3, j = within & 7;
    int kcN = K >> 5;
    int kc = frag % kcN, T = frag / kcN;
    int n = T * 16 + (lane & 15);
    int k = kc * 32 + (lane >> 4) * 8 + j;
    dst[idx] = (__bf16)W[(size_t)n * K + k];
}

// Block = 8 waves (512 threads), 32 batch samples, one direction, all 50 steps.
// Wave w owns hidden cols j in [w*16, w*16+16) for ALL four gates.
// Weights live in VGPRs (24 x bf16x8 = 96 VGPRs/lane), loaded once before t-loop.
// x_{t+1} prefetched into registers so global latency hides behind MFMA+cell.
__launch_bounds__(512)
__global__ void k_lstm(const float* __restrict__ ts, const __bf16* __restrict__ w2frag,
                       const float* __restrict__ b_f, const float* __restrict__ b_b,
                       float* __restrict__ temporal) {
    int dir = blockIdx.y;
    int btile = blockIdx.x;    // 0..127
    int tid = threadIdx.x;
    int w = tid >> 6;          // wave 0..7
    int lane = tid & 63;
    int col = lane & 15, quad = lane >> 4;

    __shared__ __align__(16) __bf16 A[32][200];   // [m][k], K=192 padded to 200

    // zero h region (k = 64..191)
    for (int i = tid; i < 32 * 128; i += 512) {
        A[i >> 7][64 + (i & 127)] = (__bf16)0.0f;
    }

    const float* bias = dir ? b_b : b_f;
    float bv[4];
#pragma unroll
    for (int g = 0; g < 4; g++) {
        bv[g] = bias[g * 128 + w * 16 + col];
    }

    // weights -> registers, once
    const __bf16* wbase = w2frag + (size_t)dir * 98304 + (size_t)w * 12288;
    bf16x8 wreg[24];
#pragma unroll
    for (int f = 0; f < 24; f++) {
        wreg[f] = *(const bf16x8*)(wbase + (f << 9) + lane * 8);
    }

    // x staging: thread -> row sm = tid>>4, cols [sc4, sc4+4)
    int sm = tid >> 4, sc4 = (tid & 15) * 4;
    const float* xbase = ts + ((size_t)(btile * 32 + sm) * SEQ) * INP + sc4;
    f32x4 xpre = *(const f32x4*)(xbase + (size_t)(dir ? (SEQ - 1) : 0) * INP);

    f32x4 c_reg[2], hsum[2];
#pragma unroll
    for (int s = 0; s < 2; s++) {
        c_reg[s] = (f32x4){0.f, 0.f, 0.f, 0.f};
        hsum[s]  = (f32x4){0.f, 0.f, 0.f, 0.f};
    }
    __syncthreads();

    for (int t = 0; t < SEQ; t++) {
        // write prefetched x_t to LDS
        {
            bf16x4 xv;
            xv[0] = (__bf16)xpre.x; xv[1] = (__bf16)xpre.y;
            xv[2] = (__bf16)xpre.z; xv[3] = (__bf16)xpre.w;
            *(bf16x4*)&A[sm][sc4] = xv;
        }
        // prefetch x_{t+1} (consumed at next iteration's LDS write)
        if (t + 1 < SEQ) {
            int tt = dir ? (SEQ - 2 - t) : (t + 1);
            xpre = *(const f32x4*)(xbase + (size_t)tt * INP);
        }
        __syncthreads();

        f32x4 acc[8];
#pragma unroll
        for (int g = 0; g < 4; g++) {
            f32x4 z = (f32x4){bv[g], bv[g], bv[g], bv[g]};
            acc[g * 2] = z;
            acc[g * 2 + 1] = z;
        }
#pragma unroll
        for (int kc = 0; kc < 6; kc++) {
            bf16x8 a0 = *(const bf16x8*)&A[col][kc * 32 + quad * 8];
            bf16x8 a1 = *(const bf16x8*)&A[16 + col][kc * 32 + quad * 8];
#pragma unroll
            for (int g = 0; g < 4; g++) {
                bf16x8 bfrag = wreg[g * 6 + kc];
                acc[g * 2]     = __builtin_amdgcn_mfma_f32_16x16x32_bf16(a0, bfrag, acc[g * 2], 0, 0, 0);
                acc[g * 2 + 1] = __builtin_amdgcn_mfma_f32_16x16x32_bf16(a1, bfrag, acc[g * 2 + 1], 0, 0, 0);
            }
        }
        __syncthreads();   // everyone's A reads done before h_t overwrite

        // cell update: lane owns (b,j) pairs; i/f/g/o same lane, same reg idx
#pragma unroll
        for (int m = 0; m < 2; m++) {
#pragma unroll
            for (int r = 0; r < 4; r++) {
                float iv = acc[0 * 2 + m][r];
                float fv = acc[1 * 2 + m][r];
                float gv = acc[2 * 2 + m][r];
                float ov = acc[3 * 2 + m][r];
                float c = sigmoidf_(fv) * c_reg[m][r] + sigmoidf_(iv) * tanhf_(gv);
                float h = sigmoidf_(ov) * tanhf_(c);
                c_reg[m][r] = c;
                hsum[m][r] += h;
                A[m * 16 + quad * 4 + r][64 + w * 16 + col] = (__bf16)h;
            }
        }
    }

    // temporal[b][dir*128 + j] = mean over t of h
#pragma unroll
    for (int m = 0; m < 2; m++) {
#pragma unroll
        for (int r = 0; r < 4; r++) {
            int b = btile * 32 + m * 16 + quad * 4 + r;
            int j = w * 16 + col;
            temporal[(size_t)b * 256 + dir * 128 + j] = hsum[m][r] * (1.0f / SEQ);
        }
    }
}

// ---------------- Head (fused gate+risk1+final) ----------------

// colsum(W2) + sum(b2); w2s zeroed beforehand. 8 blocks x 256 threads.
__global__ void k_w2sum(const float* __restrict__ W2, const float* __restrict__ b2,
                        float* __restrict__ w2s) {
    int k = threadIdx.x;
    int bb = blockIdx.x;
    float s = 0.0f;
#pragma unroll
    for (int n = 0; n < 32; n++) s += W2[(size_t)(bb * 32 + n) * 256 + k];
    atomicAdd(&w2s[k], s);
    if (bb == 0) {
        __shared__ float red[256];
        red[k] = b2[k];
        __syncthreads();
        for (int st = 128; st > 0; st >>= 1) {
            if (k < st) red[k] += red[k + st];
            __syncthreads();
        }
        if (k == 0) atomicAdd(&w2s[256], red[0]);
    }
}

// One block = 16 samples, 4 waves. Wave w owns out cols [w*64, w*64+64) (4 tiles).
// cat(bf16, LDS) -> gate MFMA (K=512) -> sigmoid/merge -> mbuf(bf16, LDS)
// -> risk1 MFMA (K=256) -> tanh -> dot w2s -> cross-lane reduce -> sigmoid.
__launch_bounds__(256)
__global__ void k_head(const float* __restrict__ structb, const float* __restrict__ temporal,
                       const __bf16* __restrict__ gwp, const __bf16* __restrict__ w1p,
                       const float* __restrict__ gate_b, const float* __restrict__ risk_b1,
                       const float* __restrict__ w2s, float* __restrict__ out) {
    int bt = blockIdx.x;
    int tid = threadIdx.x;
    int w = tid >> 6, lane = tid & 63;
    int col = lane & 15, quad = lane >> 4;

    __shared__ __align__(16) __bf16 cat[16][520];
    __shared__ __align__(16) __bf16 mbuf[16][264];
    __shared__ float sacc[16];

    for (int i = tid; i < 16 * 512; i += 256) {
        int m = i >> 9, k = i & 511;
        int b = bt * 16 + m;
        float v = (k < 256) ? structb[(size_t)b * 256 + k]
                            : temporal[(size_t)b * 256 + (k - 256)];
        cat[m][k] = (__bf16)v;
    }
    if (tid < 16) sacc[tid] = 0.0f;
    __syncthreads();

    // gate GEMM: K=512 (16 kc-chunks)
    f32x4 acc[4];
#pragma unroll
    for (int ct = 0; ct < 4; ct++) {
        float b = gate_b[w * 64 + ct * 16 + col];
        acc[ct] = (f32x4){b, b, b, b};
    }
#pragma unroll
    for (int kc = 0; kc < 16; kc++) {
        bf16x8 a = *(const bf16x8*)&cat[col][kc * 32 + quad * 8];
#pragma unroll
        for (int ct = 0; ct < 4; ct++) {
            bf16x8 bf = *(const bf16x8*)(gwp + (((w * 4 + ct) * 16 + kc) << 9) + lane * 8);
            acc[ct] = __builtin_amdgcn_mfma_f32_16x16x32_bf16(a, bf, acc[ct], 0, 0, 0);
        }
    }
    // sigmoid + merge -> mbuf
#pragma unroll
    for (int ct = 0; ct < 4; ct++) {
        int n = w * 64 + ct * 16 + col;
#pragma unroll
        for (int r = 0; r < 4; r++) {
            int m = quad * 4 + r;
            int b = bt * 16 + m;
            float g = sigmoidf_(acc[ct][r]);
            float s = structb[(size_t)b * 256 + n];
            float tm = temporal[(size_t)b * 256 + n];
            mbuf[m][n] = (__bf16)(g * s + (1.0f - g) * tm);
        }
    }
    __syncthreads();

    // risk1 GEMM: K=256 (8 kc-chunks)
    f32x4 acc2[4];
#pragma unroll
    for (int ct = 0; ct < 4; ct++) {
        float b = risk_b1[w * 64 + ct * 16 + col];
        acc2[ct] = (f32x4){b, b, b, b};
    }
#pragma unroll
    for (int kc = 0; kc < 8; kc++) {
        bf16x8 a = *(const bf16x8*)&mbuf[col][kc * 32 + quad * 8];
#pragma unroll
        for (int ct = 0; ct < 4; ct++) {
            bf16x8 bf = *(const bf16x8*)(w1p + (((w * 4 + ct) * 8 + kc) << 9) + lane * 8);
            acc2[ct] = __builtin_amdgcn_mfma_f32_16x16x32_bf16(a, bf, acc2[ct], 0, 0, 0);
        }
    }
    // tanh + dot with w2s, reduce across the 16 lanes of each quad-group
    float part[4] = {0.f, 0.f, 0.f, 0.f};
#pragma unroll
    for (int ct = 0; ct < 4; ct++) {
        int n = w * 64 + ct * 16 + col;
        float wv = w2s[n];
#pragma unroll
        for (int r = 0; r < 4; r++) {
            part[r] += tanhf_(acc2[ct][r]) * wv;
        }
    }
#pragma unroll
    for (int off = 1; off < 16; off <<= 1) {
#pragma unroll
        for (int r = 0; r < 4; r++) part[r] += __shfl_xor(part[r], off, 64);
    }
    if (col == 0) {
#pragma unroll
        for (int r = 0; r < 4; r++) atomicAdd(&sacc[quad * 4 + r], part[r]);
    }
    __syncthreads();
    if (tid < 16) out[bt * 16 + tid] = sigmoidf_(sacc[tid] + w2s[256]);
}

// ---------------- launch ----------------

extern "C" void kernel_launch(void* const* d_in, const int* in_sizes, int n_in,
                              void* d_out, int out_size, void* d_ws, size_t ws_size,
                              hipStream_t stream) {
    const float* ts       = (const float*)d_in[0];
    const float* node_emb = (const float*)d_in[1];
    const float* rel_w    = (const float*)d_in[2];
    const float* gate_W   = (const float*)d_in[3];
    const float* gate_b   = (const float*)d_in[4];
    const float* risk_W1  = (const float*)d_in[5];
    const float* risk_b1  = (const float*)d_in[6];
    const float* risk_W2  = (const float*)d_in[7];
    const float* risk_b2  = (const float*)d_in[8];
    const float* Wih_f    = (const float*)d_in[9];
    const float* Whh_f    = (const float*)d_in[10];
    const float* b_f      = (const float*)d_in[11];
    const float* Wih_b    = (const float*)d_in[12];
    const float* Whh_b    = (const float*)d_in[13];
    const float* b_b      = (const float*)d_in[14];
    const int* edge_index = (const int*)d_in[15];
    const int* edge_type  = (const int*)d_in[16];
    const int* node_idx   = (const int*)d_in[17];
    const int* head = edge_index;
    const int* tail = edge_index + N_EDGES;
    float* out = (float*)d_out;

    char* ws = (char*)d_ws;
    const size_t o_deg      = 0;                            // 50000 int
    const size_t o_bsum     = 200704;                       // 196 int -> pad 1024
    const size_t o_boff     = o_bsum + 1024;                // 256 int
    const size_t o_offsets  = o_boff + 1024;                // 50001 int -> pad 200960
    const size_t o_cursor   = o_offsets + 200960;           // 50000 int
    const size_t o_sorted   = o_cursor + 200704;            // 300000 int
    const size_t o_out1     = o_sorted + 1200128;           // 51,200,000 B
    const size_t o_temporal = o_out1 + 51200000;            // 4 MB
    const size_t o_struct   = o_temporal + 4194304;         // 4 MB
    const size_t o_gwp      = o_struct + 4194304;           // 262144 B (gate_W bf16 frags)
    const size_t o_w1p      = o_gwp + 262144;               // 131072 B (risk_W1 bf16 frags)
    const size_t o_w2s      = o_w1p + 131072;               // 257 f -> pad 2048
    const size_t o_w2frag   = o_w2s + 2048;                 // 393216 B

    int*    deg      = (int*)(ws + o_deg);
    int*    bsum     = (int*)(ws + o_bsum);
    int*    boff     = (int*)(ws + o_boff);
    int*    offsets  = (int*)(ws + o_offsets);
    int*    cursor   = (int*)(ws + o_cursor);
    int*    sorted   = (int*)(ws + o_sorted);
    float*  out1     = (float*)(ws + o_out1);
    float*  temporal = (float*)(ws + o_temporal);
    float*  structb  = (float*)(ws + o_struct);
    __bf16* gwp      = (__bf16*)(ws + o_gwp);
    __bf16* w1p      = (__bf16*)(ws + o_w1p);
    float*  w2s      = (float*)(ws + o_w2s);
    __bf16* w2frag   = (__bf16*)(ws + o_w2frag);

    hipMemsetAsync(deg, 0, N_NODES * sizeof(int), stream);
    hipMemsetAsync(w2s, 0, 2048, stream);

    // prep (independent of main chain)
    k_w2frag<<<768, 256, 0, stream>>>(Wih_f, Whh_f, Wih_b, Whh_b, w2frag);
    k_packw<<<512, 256, 0, stream>>>(gate_W, gwp, 512, 256 * 512);
    k_packw<<<256, 256, 0, stream>>>(risk_W1, w1p, 256, 256 * 256);
    k_w2sum<<<8, 256, 0, stream>>>(risk_W2, risk_b2, w2s);
    // sort
    k_hist<<<(N_EDGES + 255) / 256, 256, 0, stream>>>(head, deg);
    k_bsum<<<SCAN_BLOCKS, 256, 0, stream>>>(deg, bsum);
    k_scanb<<<1, 256, 0, stream>>>(bsum, boff);
    k_scan2<<<SCAN_BLOCKS, 256, 0, stream>>>(deg, boff, offsets, cursor);
    k_place<<<(N_EDGES + 255) / 256, 256, 0, stream>>>(head, tail, edge_type, cursor, sorted);
    // main chain
    k_gather<<<(N_NODES + 3) / 4, 256, 0, stream>>>(offsets, sorted, rel_w, node_emb, out1);
    k_lstm<<<dim3(BATCH / 32, 2), 512, 0, stream>>>(ts, w2frag, b_f, b_b, temporal);
    k_gather2<<<BATCH / 4, 256, 0, stream>>>(node_idx, offsets, sorted, rel_w, out1, node_emb, structb);
    k_head<<<BATCH / 16, 256, 0, stream>>>(structb, temporal, gwp, w1p, gate_b, risk_b1, w2s, out);
}

// Round 7
// 353.898 us; speedup vs baseline: 1.5048x; 1.0108x over previous
//
#include <hip/hip_runtime.h>

#define N_NODES 50000
#define N_EDGES 300000
#define DIM 256
#define HID 128
#define INP 64
#define BATCH 4096
#define SEQ 50
#define SCAN_BLOCKS 196   // ceil(50000/256)

typedef float f32x2 __attribute__((ext_vector_type(2)));
typedef float f32x4 __attribute__((ext_vector_type(4)));
typedef __bf16 bf16x2 __attribute__((ext_vector_type(2)));
typedef __bf16 bf16x8 __attribute__((ext_vector_type(8)));

// fast activations: v_rcp_f32 instead of IEEE divide (~1 ulp, inf-safe)
__device__ __forceinline__ float sigmoidf_(float x) {
    return __builtin_amdgcn_rcpf(1.0f + __expf(-x));
}
__device__ __forceinline__ float tanhf_(float x) {
    return 1.0f - 2.0f * __builtin_amdgcn_rcpf(1.0f + __expf(2.0f * x));
}

// ---------------- GCN: counting sort by head ----------------

__global__ void k_hist(const int* __restrict__ head, int* __restrict__ deg) {
    int e = blockIdx.x * 256 + threadIdx.x;
    if (e < N_EDGES) atomicAdd(&deg[head[e]], 1);
}

__global__ void k_bsum(const int* __restrict__ deg, int* __restrict__ bsum) {
    __shared__ int red[256];
    int n = blockIdx.x * 256 + threadIdx.x;
    red[threadIdx.x] = (n < N_NODES) ? deg[n] : 0;
    __syncthreads();
    for (int st = 128; st > 0; st >>= 1) {
        if (threadIdx.x < st) red[threadIdx.x] += red[threadIdx.x + st];
        __syncthreads();
    }
    if (threadIdx.x == 0) bsum[blockIdx.x] = red[0];
}

__global__ void k_scanb(const int* __restrict__ bsum, int* __restrict__ boff) {
    __shared__ int s[256];
    int i = threadIdx.x;
    int v = (i < SCAN_BLOCKS) ? bsum[i] : 0;
    s[i] = v;
    __syncthreads();
    for (int st = 1; st < 256; st <<= 1) {
        int add = (i >= st) ? s[i - st] : 0;
        __syncthreads();
        s[i] += add;
        __syncthreads();
    }
    boff[i] = s[i] - v;   // exclusive
}

__global__ void k_scan2(const int* __restrict__ deg, const int* __restrict__ boff,
                        int* __restrict__ offsets, int* __restrict__ cursor) {
    __shared__ int s[256];
    int i = threadIdx.x;
    int n = blockIdx.x * 256 + i;
    int v = (n < N_NODES) ? deg[n] : 0;
    s[i] = v;
    __syncthreads();
    for (int st = 1; st < 256; st <<= 1) {
        int add = (i >= st) ? s[i - st] : 0;
        __syncthreads();
        s[i] += add;
        __syncthreads();
    }
    if (n < N_NODES) {
        int off = boff[blockIdx.x] + s[i] - v;
        offsets[n] = off;
        cursor[n] = off;
    }
    if (n == 0) offsets[N_NODES] = N_EDGES;
}

__global__ void k_place(const int* __restrict__ head, const int* __restrict__ tail,
                        const int* __restrict__ etype, int* __restrict__ cursor,
                        int* __restrict__ sorted) {
    int e = blockIdx.x * 256 + threadIdx.x;
    if (e >= N_EDGES) return;
    int h = head[e];
    int pos = atomicAdd(&cursor[h], 1);
    sorted[pos] = tail[e] | (etype[e] << 16);   // tail<65536, etype<32
}

// Mark nodes whose out1 is actually consumed: batch nodes + their in-edge tails.
__global__ void k_flag(const int* __restrict__ nidx, const int* __restrict__ offsets,
                       const int* __restrict__ sorted, char* __restrict__ flag) {
    int b = blockIdx.x * 256 + threadIdx.x;
    if (b >= BATCH) return;
    int n = nidx[b];
    flag[n] = 1;
    int s = offsets[n], e = offsets[n + 1];
    for (int j = s; j < e; j++) flag[sorted[j] & 0xFFFF] = 1;
}

// Hop 1: one wave per node; lane holds dims [4*lane, 4*lane+4). No atomics.
// Only computes flagged nodes (~43% of graph).
__global__ void k_gather(const int* __restrict__ offsets, const int* __restrict__ sorted,
                         const float* __restrict__ relw, const float* __restrict__ src,
                         const char* __restrict__ flag, float* __restrict__ dst) {
    int tid = threadIdx.x;
    int w = tid >> 6, lane = tid & 63;
    int n = blockIdx.x * 4 + w;
    if (n >= N_NODES) return;
    if (!flag[n]) return;
    int s = offsets[n], e = offsets[n + 1];
    f32x4 acc0 = (f32x4){0.f, 0.f, 0.f, 0.f};
    f32x4 acc1 = (f32x4){0.f, 0.f, 0.f, 0.f};
    f32x4 acc2 = (f32x4){0.f, 0.f, 0.f, 0.f};
    f32x4 acc3 = (f32x4){0.f, 0.f, 0.f, 0.f};
    int j = s;
    for (; j + 4 <= e; j += 4) {
        int p0 = sorted[j], p1 = sorted[j + 1], p2 = sorted[j + 2], p3 = sorted[j + 3];
        f32x4 v0 = *(const f32x4*)(src + (size_t)(p0 & 0xFFFF) * DIM + lane * 4);
        f32x4 v1 = *(const f32x4*)(src + (size_t)(p1 & 0xFFFF) * DIM + lane * 4);
        f32x4 v2 = *(const f32x4*)(src + (size_t)(p2 & 0xFFFF) * DIM + lane * 4);
        f32x4 v3 = *(const f32x4*)(src + (size_t)(p3 & 0xFFFF) * DIM + lane * 4);
        acc0 += v0 * *(const f32x4*)(relw + (p0 >> 16) * DIM + lane * 4);
        acc1 += v1 * *(const f32x4*)(relw + (p1 >> 16) * DIM + lane * 4);
        acc2 += v2 * *(const f32x4*)(relw + (p2 >> 16) * DIM + lane * 4);
        acc3 += v3 * *(const f32x4*)(relw + (p3 >> 16) * DIM + lane * 4);
    }
    for (; j < e; j++) {
        int p0 = sorted[j];
        f32x4 v0 = *(const f32x4*)(src + (size_t)(p0 & 0xFFFF) * DIM + lane * 4);
        acc0 += v0 * *(const f32x4*)(relw + (p0 >> 16) * DIM + lane * 4);
    }
    acc0 = (acc0 + acc1) + (acc2 + acc3);
    float inv = 1.0f / fmaxf((float)(e - s), 1.0f);
    *(f32x4*)(dst + (size_t)n * DIM + lane * 4) = acc0 * inv;
}

// Hop 2 only at batch nodes, fused with struct = (emb + out1 + out2)/3.
__global__ void k_gather2(const int* __restrict__ nidx, const int* __restrict__ offsets,
                          const int* __restrict__ sorted, const float* __restrict__ relw,
                          const float* __restrict__ out1, const float* __restrict__ emb,
                          float* __restrict__ structb) {
    int tid = threadIdx.x;
    int w = tid >> 6, lane = tid & 63;
    int b = blockIdx.x * 4 + w;          // grid = 1024 blocks, exact
    int n = nidx[b];
    int s = offsets[n], e = offsets[n + 1];
    f32x4 acc0 = (f32x4){0.f, 0.f, 0.f, 0.f};
    f32x4 acc1 = (f32x4){0.f, 0.f, 0.f, 0.f};
    f32x4 acc2 = (f32x4){0.f, 0.f, 0.f, 0.f};
    f32x4 acc3 = (f32x4){0.f, 0.f, 0.f, 0.f};
    int j = s;
    for (; j + 4 <= e; j += 4) {
        int p0 = sorted[j], p1 = sorted[j + 1], p2 = sorted[j + 2], p3 = sorted[j + 3];
        f32x4 v0 = *(const f32x4*)(out1 + (size_t)(p0 & 0xFFFF) * DIM + lane * 4);
        f32x4 v1 = *(const f32x4*)(out1 + (size_t)(p1 & 0xFFFF) * DIM + lane * 4);
        f32x4 v2 = *(const f32x4*)(out1 + (size_t)(p2 & 0xFFFF) * DIM + lane * 4);
        f32x4 v3 = *(const f32x4*)(out1 + (size_t)(p3 & 0xFFFF) * DIM + lane * 4);
        acc0 += v0 * *(const f32x4*)(relw + (p0 >> 16) * DIM + lane * 4);
        acc1 += v1 * *(const f32x4*)(relw + (p1 >> 16) * DIM + lane * 4);
        acc2 += v2 * *(const f32x4*)(relw + (p2 >> 16) * DIM + lane * 4);
        acc3 += v3 * *(const f32x4*)(relw + (p3 >> 16) * DIM + lane * 4);
    }
    for (; j < e; j++) {
        int p0 = sorted[j];
        f32x4 v0 = *(const f32x4*)(out1 + (size_t)(p0 & 0xFFFF) * DIM + lane * 4);
        acc0 += v0 * *(const f32x4*)(relw + (p0 >> 16) * DIM + lane * 4);
    }
    acc0 = (acc0 + acc1) + (acc2 + acc3);
    float inv = 1.0f / fmaxf((float)(e - s), 1.0f);
    f32x4 o2 = acc0 * inv;
    f32x4 e0 = *(const f32x4*)(emb + (size_t)n * DIM + lane * 4);
    f32x4 o1 = *(const f32x4*)(out1 + (size_t)n * DIM + lane * 4);
    *(f32x4*)(structb + (size_t)b * DIM + lane * 4) = (e0 + o1 + o2) * (1.0f / 3.0f);
}

// ---------------- BiLSTM ----------------
// Pack W = [Wih | Whh] (bf16, K=192) into MFMA B-fragment order, 512-elem frags:
// per dir: frag = (w*4+g)*6+kc  (w=wave 0..7, g=gate 0..3, kc=0..5)
// within-frag = lane*8+j ; value = W[n][k],
//   n = g*128 + w*16 + (lane&15),  k = kc*32 + (lane>>4)*8 + j
__global__ void k_w2frag(const float* __restrict__ Wih_f, const float* __restrict__ Whh_f,
                         const float* __restrict__ Wih_b, const float* __restrict__ Whh_b,
                         __bf16* __restrict__ w2) {
    int idx = blockIdx.x * 256 + threadIdx.x;   // 2 * 192 * 512 = 196608
    int dir = idx / 98304;
    int rem = idx % 98304;
    int frag = rem >> 9;        // 0..191
    int within = rem & 511;
    int lane = within >> 3, j = within & 7;
    int kc = frag % 6;
    int wg = frag / 6;          // 0..31
    int g = wg & 3, w = wg >> 2;
    int n = g * 128 + w * 16 + (lane & 15);
    int k = kc * 32 + (lane >> 4) * 8 + j;
    const float* Wih = dir ? Wih_b : Wih_f;
    const float* Whh = dir ? Whh_b : Whh_f;
    float v = (k < 64) ? Wih[n * 64 + k] : Whh[n * 128 + (k - 64)];
    w2[idx] = (__bf16)v;
}

// Generic packer: W[N][K] fp32 -> bf16 MFMA B-frags.
__global__ void k_packw(const float* __restrict__ W, __bf16* __restrict__ dst,
                        int K, int total) {
    int idx = blockIdx.x * 256 + threadIdx.x;
    if (idx >= total) return;
    int frag = idx >> 9, within = idx & 511;
    int lane = within >> 3, j = within & 7;
    int kcN = K >> 5;
    int kc = frag % kcN, T = frag / kcN;
    int n = T * 16 + (lane & 15);
    int k = kc * 32 + (lane >> 4) * 8 + j;
    dst[idx] = (__bf16)W[(size_t)n * K + k];
}

// Block = 8 waves (512 thr), M=16 samples, one direction, all 50 steps.
// Wave w owns hidden cols [w*16, w*16+16) for ALL four gates (24 MFMA/step).
// Weights in VGPRs (24 x bf16x8). Grid (256,2) = 512 blocks -> 2 blocks/CU if
// registers allow 4 waves/SIMD; independent blocks overlap MFMA vs cell-VALU.
__launch_bounds__(512)
__global__ void k_lstm(const float* __restrict__ ts, const __bf16* __restrict__ w2frag,
                       const float* __restrict__ b_f, const float* __restrict__ b_b,
                       float* __restrict__ temporal) {
    int dir = blockIdx.y;
    int btile = blockIdx.x;    // 0..255
    int tid = threadIdx.x;
    int w = tid >> 6;          // wave 0..7
    int lane = tid & 63;
    int col = lane & 15, quad = lane >> 4;

    __shared__ __align__(16) __bf16 A[16][200];   // [m][k], K=192 padded to 200

    // zero h region (k = 64..191): 16*128 elems
    for (int i = tid; i < 16 * 128; i += 512) {
        A[i >> 7][64 + (i & 127)] = (__bf16)0.0f;
    }

    const float* bias = dir ? b_b : b_f;
    float bv[4];
#pragma unroll
    for (int g = 0; g < 4; g++) {
        bv[g] = bias[g * 128 + w * 16 + col];
    }

    // weights -> registers, once (same packing as before: wave w slice)
    const __bf16* wbase = w2frag + (size_t)dir * 98304 + (size_t)w * 12288;
    bf16x8 wreg[24];
#pragma unroll
    for (int f = 0; f < 24; f++) {
        wreg[f] = *(const bf16x8*)(wbase + (f << 9) + lane * 8);
    }

    // x staging: 16 rows x 64 cols; thread -> row sm = tid>>5, col pair sc=(tid&31)*2
    int sm = tid >> 5, sc = (tid & 31) * 2;
    const float* xbase = ts + ((size_t)(btile * 16 + sm) * SEQ) * INP + sc;
    f32x2 xpre = *(const f32x2*)(xbase + (size_t)(dir ? (SEQ - 1) : 0) * INP);

    f32x4 c_reg = (f32x4){0.f, 0.f, 0.f, 0.f};
    f32x4 hsum  = (f32x4){0.f, 0.f, 0.f, 0.f};
    int hoff = 64 + w * 16 + col;
    __syncthreads();

    for (int t = 0; t < SEQ; t++) {
        // write prefetched x_t to LDS
        {
            bf16x2 xv;
            xv[0] = (__bf16)xpre.x; xv[1] = (__bf16)xpre.y;
            *(bf16x2*)&A[sm][sc] = xv;
        }
        if (t + 1 < SEQ) {
            int tt = dir ? (SEQ - 2 - t) : (t + 1);
            xpre = *(const f32x2*)(xbase + (size_t)tt * INP);
        }
        __syncthreads();

        f32x4 acc[4];
#pragma unroll
        for (int g = 0; g < 4; g++) {
            acc[g] = (f32x4){bv[g], bv[g], bv[g], bv[g]};
        }
#pragma unroll
        for (int kc = 0; kc < 6; kc++) {
            bf16x8 a0 = *(const bf16x8*)&A[col][kc * 32 + quad * 8];
#pragma unroll
            for (int g = 0; g < 4; g++) {
                acc[g] = __builtin_amdgcn_mfma_f32_16x16x32_bf16(a0, wreg[g * 6 + kc], acc[g], 0, 0, 0);
            }
        }
        __syncthreads();   // all A reads done before h_t overwrite

        // cell update: lane owns (b=quad*4+r, j=w*16+col); i/f/g/o same lane+reg
#pragma unroll
        for (int r = 0; r < 4; r++) {
            float iv = acc[0][r];
            float fv = acc[1][r];
            float gv = acc[2][r];
            float ov = acc[3][r];
            float c = sigmoidf_(fv) * c_reg[r] + sigmoidf_(iv) * tanhf_(gv);
            float h = sigmoidf_(ov) * tanhf_(c);
            c_reg[r] = c;
            hsum[r] += h;
            A[quad * 4 + r][hoff] = (__bf16)h;
        }
    }

    // temporal[b][dir*128 + j] = mean over t of h
#pragma unroll
    for (int r = 0; r < 4; r++) {
        int b = btile * 16 + quad * 4 + r;
        int j = w * 16 + col;
        temporal[(size_t)b * 256 + dir * 128 + j] = hsum[r] * (1.0f / SEQ);
    }
}

// ---------------- Head (fused gate+risk1+final) ----------------

// colsum(W2) + sum(b2); w2s zeroed beforehand. 8 blocks x 256 threads.
__global__ void k_w2sum(const float* __restrict__ W2, const float* __restrict__ b2,
                        float* __restrict__ w2s) {
    int k = threadIdx.x;
    int bb = blockIdx.x;
    float s = 0.0f;
#pragma unroll
    for (int n = 0; n < 32; n++) s += W2[(size_t)(bb * 32 + n) * 256 + k];
    atomicAdd(&w2s[k], s);
    if (bb == 0) {
        __shared__ float red[256];
        red[k] = b2[k];
        __syncthreads();
        for (int st = 128; st > 0; st >>= 1) {
            if (k < st) red[k] += red[k + st];
            __syncthreads();
        }
        if (k == 0) atomicAdd(&w2s[256], red[0]);
    }
}

// One block = 16 samples, 4 waves. Wave w owns out cols [w*64, w*64+64).
__launch_bounds__(256)
__global__ void k_head(const float* __restrict__ structb, const float* __restrict__ temporal,
                       const __bf16* __restrict__ gwp, const __bf16* __restrict__ w1p,
                       const float* __restrict__ gate_b, const float* __restrict__ risk_b1,
                       const float* __restrict__ w2s, float* __restrict__ out) {
    int bt = blockIdx.x;
    int tid = threadIdx.x;
    int w = tid >> 6, lane = tid & 63;
    int col = lane & 15, quad = lane >> 4;

    __shared__ __align__(16) __bf16 cat[16][520];
    __shared__ __align__(16) __bf16 mbuf[16][264];
    __shared__ float sacc[16];

    for (int i = tid; i < 16 * 512; i += 256) {
        int m = i >> 9, k = i & 511;
        int b = bt * 16 + m;
        float v = (k < 256) ? structb[(size_t)b * 256 + k]
                            : temporal[(size_t)b * 256 + (k - 256)];
        cat[m][k] = (__bf16)v;
    }
    if (tid < 16) sacc[tid] = 0.0f;
    __syncthreads();

    // gate GEMM: K=512 (16 kc-chunks)
    f32x4 acc[4];
#pragma unroll
    for (int ct = 0; ct < 4; ct++) {
        float b = gate_b[w * 64 + ct * 16 + col];
        acc[ct] = (f32x4){b, b, b, b};
    }
#pragma unroll
    for (int kc = 0; kc < 16; kc++) {
        bf16x8 a = *(const bf16x8*)&cat[col][kc * 32 + quad * 8];
#pragma unroll
        for (int ct = 0; ct < 4; ct++) {
            bf16x8 bf = *(const bf16x8*)(gwp + (((w * 4 + ct) * 16 + kc) << 9) + lane * 8);
            acc[ct] = __builtin_amdgcn_mfma_f32_16x16x32_bf16(a, bf, acc[ct], 0, 0, 0);
        }
    }
    // sigmoid + merge -> mbuf
#pragma unroll
    for (int ct = 0; ct < 4; ct++) {
        int n = w * 64 + ct * 16 + col;
#pragma unroll
        for (int r = 0; r < 4; r++) {
            int m = quad * 4 + r;
            int b = bt * 16 + m;
            float g = sigmoidf_(acc[ct][r]);
            float s = structb[(size_t)b * 256 + n];
            float tm = temporal[(size_t)b * 256 + n];
            mbuf[m][n] = (__bf16)(g * s + (1.0f - g) * tm);
        }
    }
    __syncthreads();

    // risk1 GEMM: K=256 (8 kc-chunks)
    f32x4 acc2[4];
#pragma unroll
    for (int ct = 0; ct < 4; ct++) {
        float b = risk_b1[w * 64 + ct * 16 + col];
        acc2[ct] = (f32x4){b, b, b, b};
    }
#pragma unroll
    for (int kc = 0; kc < 8; kc++) {
        bf16x8 a = *(const bf16x8*)&mbuf[col][kc * 32 + quad * 8];
#pragma unroll
        for (int ct = 0; ct < 4; ct++) {
            bf16x8 bf = *(const bf16x8*)(w1p + (((w * 4 + ct) * 8 + kc) << 9) + lane * 8);
            acc2[ct] = __builtin_amdgcn_mfma_f32_16x16x32_bf16(a, bf, acc2[ct], 0, 0, 0);
        }
    }
    // tanh + dot with w2s, reduce across the 16 lanes of each quad-group
    float part[4] = {0.f, 0.f, 0.f, 0.f};
#pragma unroll
    for (int ct = 0; ct < 4; ct++) {
        int n = w * 64 + ct * 16 + col;
        float wv = w2s[n];
#pragma unroll
        for (int r = 0; r < 4; r++) {
            part[r] += tanhf_(acc2[ct][r]) * wv;
        }
    }
#pragma unroll
    for (int off = 1; off < 16; off <<= 1) {
#pragma unroll
        for (int r = 0; r < 4; r++) part[r] += __shfl_xor(part[r], off, 64);
    }
    if (col == 0) {
#pragma unroll
        for (int r = 0; r < 4; r++) atomicAdd(&sacc[quad * 4 + r], part[r]);
    }
    __syncthreads();
    if (tid < 16) out[bt * 16 + tid] = sigmoidf_(sacc[tid] + w2s[256]);
}

// ---------------- launch ----------------

extern "C" void kernel_launch(void* const* d_in, const int* in_sizes, int n_in,
                              void* d_out, int out_size, void* d_ws, size_t ws_size,
                              hipStream_t stream) {
    const float* ts       = (const float*)d_in[0];
    const float* node_emb = (const float*)d_in[1];
    const float* rel_w    = (const float*)d_in[2];
    const float* gate_W   = (const float*)d_in[3];
    const float* gate_b   = (const float*)d_in[4];
    const float* risk_W1  = (const float*)d_in[5];
    const float* risk_b1  = (const float*)d_in[6];
    const float* risk_W2  = (const float*)d_in[7];
    const float* risk_b2  = (const float*)d_in[8];
    const float* Wih_f    = (const float*)d_in[9];
    const float* Whh_f    = (const float*)d_in[10];
    const float* b_f      = (const float*)d_in[11];
    const float* Wih_b    = (const float*)d_in[12];
    const float* Whh_b    = (const float*)d_in[13];
    const float* b_b      = (const float*)d_in[14];
    const int* edge_index = (const int*)d_in[15];
    const int* edge_type  = (const int*)d_in[16];
    const int* node_idx   = (const int*)d_in[17];
    const int* head = edge_index;
    const int* tail = edge_index + N_EDGES;
    float* out = (float*)d_out;

    char* ws = (char*)d_ws;
    const size_t o_deg      = 0;                            // 50000 int
    const size_t o_flagbuf  = 200704;                       // 50000 char -> pad 50176
    const size_t o_bsum     = o_flagbuf + 50176;            // 196 int -> pad 1024
    const size_t o_boff     = o_bsum + 1024;                // 256 int
    const size_t o_offsets  = o_boff + 1024;                // 50001 int -> pad 200960
    const size_t o_cursor   = o_offsets + 200960;           // 50000 int
    const size_t o_sorted   = o_cursor + 200704;            // 300000 int
    const size_t o_out1     = o_sorted + 1200128;           // 51,200,000 B
    const size_t o_temporal = o_out1 + 51200000;            // 4 MB
    const size_t o_struct   = o_temporal + 4194304;         // 4 MB
    const size_t o_gwp      = o_struct + 4194304;           // 262144 B
    const size_t o_w1p      = o_gwp + 262144;               // 131072 B
    const size_t o_w2s      = o_w1p + 131072;               // 257 f -> pad 2048
    const size_t o_w2frag   = o_w2s + 2048;                 // 393216 B

    int*    deg      = (int*)(ws + o_deg);
    char*   flag     = (char*)(ws + o_flagbuf);
    int*    bsum     = (int*)(ws + o_bsum);
    int*    boff     = (int*)(ws + o_boff);
    int*    offsets  = (int*)(ws + o_offsets);
    int*    cursor   = (int*)(ws + o_cursor);
    int*    sorted   = (int*)(ws + o_sorted);
    float*  out1     = (float*)(ws + o_out1);
    float*  temporal = (float*)(ws + o_temporal);
    float*  structb  = (float*)(ws + o_struct);
    __bf16* gwp      = (__bf16*)(ws + o_gwp);
    __bf16* w1p      = (__bf16*)(ws + o_w1p);
    float*  w2s      = (float*)(ws + o_w2s);
    __bf16* w2frag   = (__bf16*)(ws + o_w2frag);

    hipMemsetAsync(ws, 0, o_flagbuf + 50176, stream);   // deg + flag
    hipMemsetAsync(w2s, 0, 2048, stream);

    // prep (independent of main chain)
    k_w2frag<<<768, 256, 0, stream>>>(Wih_f, Whh_f, Wih_b, Whh_b, w2frag);
    k_packw<<<512, 256, 0, stream>>>(gate_W, gwp, 512, 256 * 512);
    k_packw<<<256, 256, 0, stream>>>(risk_W1, w1p, 256, 256 * 256);
    k_w2sum<<<8, 256, 0, stream>>>(risk_W2, risk_b2, w2s);
    // sort
    k_hist<<<(N_EDGES + 255) / 256, 256, 0, stream>>>(head, deg);
    k_bsum<<<SCAN_BLOCKS, 256, 0, stream>>>(deg, bsum);
    k_scanb<<<1, 256, 0, stream>>>(bsum, boff);
    k_scan2<<<SCAN_BLOCKS, 256, 0, stream>>>(deg, boff, offsets, cursor);
    k_place<<<(N_EDGES + 255) / 256, 256, 0, stream>>>(head, tail, edge_type, cursor, sorted);
    k_flag<<<BATCH / 256, 256, 0, stream>>>(node_idx, offsets, sorted, flag);
    // main chain
    k_gather<<<(N_NODES + 3) / 4, 256, 0, stream>>>(offsets, sorted, rel_w, node_emb, flag, out1);
    k_lstm<<<dim3(BATCH / 16, 2), 512, 0, stream>>>(ts, w2frag, b_f, b_b, temporal);
    k_gather2<<<BATCH / 4, 256, 0, stream>>>(node_idx, offsets, sorted, rel_w, out1, node_emb, structb);
    k_head<<<BATCH / 16, 256, 0, stream>>>(structb, temporal, gwp, w1p, gate_b, risk_b1, w2s, out);
}

// Round 8
// 338.383 us; speedup vs baseline: 1.5738x; 1.0459x over previous
//
#include <hip/hip_runtime.h>

#define N_NODES 50000
#define N_EDGES 300000
#define DIM 256
#define HID 128
#define INP 64
#define BATCH 4096
#define SEQ 50
#define SCAN_BLOCKS 196   // ceil(50000/256)

typedef float f32x2 __attribute__((ext_vector_type(2)));
typedef float f32x4 __attribute__((ext_vector_type(4)));
typedef __bf16 bf16x2 __attribute__((ext_vector_type(2)));
typedef __bf16 bf16x8 __attribute__((ext_vector_type(8)));

// fast activations: v_rcp_f32 instead of IEEE divide (~1 ulp, inf-safe)
__device__ __forceinline__ float sigmoidf_(float x) {
    return __builtin_amdgcn_rcpf(1.0f + __expf(-x));
}
__device__ __forceinline__ float tanhf_(float x) {
    return 1.0f - 2.0f * __builtin_amdgcn_rcpf(1.0f + __expf(2.0f * x));
}

// ---------------- fused prep: weight packs + w2sum + zeroing ----------------
// blocks 0..767: lstm weight frags | 768..1279: gate_W pack | 1280..1535: risk_W1
// 1536: w2 colsum | 1537..1732: zero deg | 1733..1781: zero flag
__global__ void k_prep(const float* __restrict__ Wih_f, const float* __restrict__ Whh_f,
                       const float* __restrict__ Wih_b, const float* __restrict__ Whh_b,
                       const float* __restrict__ gate_W, const float* __restrict__ risk_W1,
                       const float* __restrict__ risk_W2, const float* __restrict__ risk_b2,
                       __bf16* __restrict__ w2frag, __bf16* __restrict__ gwp,
                       __bf16* __restrict__ w1p, float* __restrict__ w2s,
                       int* __restrict__ deg, int* __restrict__ flagi) {
    __shared__ float red[256];
    int bid = blockIdx.x, tid = threadIdx.x;
    if (bid < 768) {
        // LSTM W=[Wih|Whh] -> frags: per dir frag=(w*4+g)*6+kc, within=lane*8+j
        int idx = bid * 256 + tid;              // 2*192*512 = 196608
        int dir = idx / 98304;
        int rem = idx % 98304;
        int frag = rem >> 9;
        int within = rem & 511;
        int lane = within >> 3, j = within & 7;
        int kc = frag % 6;
        int wg = frag / 6;
        int g = wg & 3, w = wg >> 2;
        int n = g * 128 + w * 16 + (lane & 15);
        int k = kc * 32 + (lane >> 4) * 8 + j;
        const float* Wih = dir ? Wih_b : Wih_f;
        const float* Whh = dir ? Whh_b : Whh_f;
        float v = (k < 64) ? Wih[n * 64 + k] : Whh[n * 128 + (k - 64)];
        w2frag[idx] = (__bf16)v;
    } else if (bid < 1280) {
        int idx = (bid - 768) * 256 + tid;      // 131072
        int frag = idx >> 9, within = idx & 511;
        int lane = within >> 3, j = within & 7;
        int kc = frag % 16, T = frag / 16;
        int n = T * 16 + (lane & 15);
        int k = kc * 32 + (lane >> 4) * 8 + j;
        gwp[idx] = (__bf16)gate_W[(size_t)n * 512 + k];
    } else if (bid < 1536) {
        int idx = (bid - 1280) * 256 + tid;     // 65536
        int frag = idx >> 9, within = idx & 511;
        int lane = within >> 3, j = within & 7;
        int kc = frag % 8, T = frag / 8;
        int n = T * 16 + (lane & 15);
        int k = kc * 32 + (lane >> 4) * 8 + j;
        w1p[idx] = (__bf16)risk_W1[(size_t)n * 256 + k];
    } else if (bid == 1536) {
        int k = tid;
        float s = 0.0f;
        for (int n = 0; n < 256; n++) s += risk_W2[(size_t)n * 256 + k];
        w2s[k] = s;
        red[k] = risk_b2[k];
        __syncthreads();
        for (int st = 128; st > 0; st >>= 1) {
            if (k < st) red[k] += red[k + st];
            __syncthreads();
        }
        if (k == 0) w2s[256] = red[0];
    } else if (bid < 1733) {
        int i = (bid - 1537) * 256 + tid;
        if (i < N_NODES) deg[i] = 0;
    } else {
        int i = (bid - 1733) * 256 + tid;       // 49*256 = 12544 ints = 50176 B
        flagi[i] = 0;
    }
}

// ---------------- GCN: counting sort by head ----------------

__global__ void k_hist(const int* __restrict__ head, int* __restrict__ deg) {
    int e = blockIdx.x * 256 + threadIdx.x;
    if (e < N_EDGES) atomicAdd(&deg[head[e]], 1);
}

__global__ void k_bsum(const int* __restrict__ deg, int* __restrict__ bsum) {
    __shared__ int red[256];
    int n = blockIdx.x * 256 + threadIdx.x;
    red[threadIdx.x] = (n < N_NODES) ? deg[n] : 0;
    __syncthreads();
    for (int st = 128; st > 0; st >>= 1) {
        if (threadIdx.x < st) red[threadIdx.x] += red[threadIdx.x + st];
        __syncthreads();
    }
    if (threadIdx.x == 0) bsum[blockIdx.x] = red[0];
}

__global__ void k_scanb(const int* __restrict__ bsum, int* __restrict__ boff) {
    __shared__ int s[256];
    int i = threadIdx.x;
    int v = (i < SCAN_BLOCKS) ? bsum[i] : 0;
    s[i] = v;
    __syncthreads();
    for (int st = 1; st < 256; st <<= 1) {
        int add = (i >= st) ? s[i - st] : 0;
        __syncthreads();
        s[i] += add;
        __syncthreads();
    }
    boff[i] = s[i] - v;   // exclusive
}

__global__ void k_scan2(const int* __restrict__ deg, const int* __restrict__ boff,
                        int* __restrict__ offsets, int* __restrict__ cursor) {
    __shared__ int s[256];
    int i = threadIdx.x;
    int n = blockIdx.x * 256 + i;
    int v = (n < N_NODES) ? deg[n] : 0;
    s[i] = v;
    __syncthreads();
    for (int st = 1; st < 256; st <<= 1) {
        int add = (i >= st) ? s[i - st] : 0;
        __syncthreads();
        s[i] += add;
        __syncthreads();
    }
    if (n < N_NODES) {
        int off = boff[blockIdx.x] + s[i] - v;
        offsets[n] = off;
        cursor[n] = off;
    }
    if (n == 0) offsets[N_NODES] = N_EDGES;
}

__global__ void k_place(const int* __restrict__ head, const int* __restrict__ tail,
                        const int* __restrict__ etype, int* __restrict__ cursor,
                        int* __restrict__ sorted) {
    int e = blockIdx.x * 256 + threadIdx.x;
    if (e >= N_EDGES) return;
    int h = head[e];
    int pos = atomicAdd(&cursor[h], 1);
    sorted[pos] = tail[e] | (etype[e] << 16);   // tail<65536, etype<32
}

// Mark nodes whose out1 is actually consumed: batch nodes + their in-edge tails.
__global__ void k_flag(const int* __restrict__ nidx, const int* __restrict__ offsets,
                       const int* __restrict__ sorted, char* __restrict__ flag) {
    int b = blockIdx.x * 256 + threadIdx.x;
    if (b >= BATCH) return;
    int n = nidx[b];
    flag[n] = 1;
    int s = offsets[n], e = offsets[n + 1];
    for (int j = s; j < e; j++) flag[sorted[j] & 0xFFFF] = 1;
}

// Hop 1: one wave per node; only flagged nodes (~43% of graph). No atomics.
__global__ void k_gather(const int* __restrict__ offsets, const int* __restrict__ sorted,
                         const float* __restrict__ relw, const float* __restrict__ src,
                         const char* __restrict__ flag, float* __restrict__ dst) {
    int tid = threadIdx.x;
    int w = tid >> 6, lane = tid & 63;
    int n = blockIdx.x * 4 + w;
    if (n >= N_NODES) return;
    if (!flag[n]) return;
    int s = offsets[n], e = offsets[n + 1];
    f32x4 acc0 = (f32x4){0.f, 0.f, 0.f, 0.f};
    f32x4 acc1 = (f32x4){0.f, 0.f, 0.f, 0.f};
    f32x4 acc2 = (f32x4){0.f, 0.f, 0.f, 0.f};
    f32x4 acc3 = (f32x4){0.f, 0.f, 0.f, 0.f};
    int j = s;
    for (; j + 4 <= e; j += 4) {
        int p0 = sorted[j], p1 = sorted[j + 1], p2 = sorted[j + 2], p3 = sorted[j + 3];
        f32x4 v0 = *(const f32x4*)(src + (size_t)(p0 & 0xFFFF) * DIM + lane * 4);
        f32x4 v1 = *(const f32x4*)(src + (size_t)(p1 & 0xFFFF) * DIM + lane * 4);
        f32x4 v2 = *(const f32x4*)(src + (size_t)(p2 & 0xFFFF) * DIM + lane * 4);
        f32x4 v3 = *(const f32x4*)(src + (size_t)(p3 & 0xFFFF) * DIM + lane * 4);
        acc0 += v0 * *(const f32x4*)(relw + (p0 >> 16) * DIM + lane * 4);
        acc1 += v1 * *(const f32x4*)(relw + (p1 >> 16) * DIM + lane * 4);
        acc2 += v2 * *(const f32x4*)(relw + (p2 >> 16) * DIM + lane * 4);
        acc3 += v3 * *(const f32x4*)(relw + (p3 >> 16) * DIM + lane * 4);
    }
    for (; j < e; j++) {
        int p0 = sorted[j];
        f32x4 v0 = *(const f32x4*)(src + (size_t)(p0 & 0xFFFF) * DIM + lane * 4);
        acc0 += v0 * *(const f32x4*)(relw + (p0 >> 16) * DIM + lane * 4);
    }
    acc0 = (acc0 + acc1) + (acc2 + acc3);
    float inv = 1.0f / fmaxf((float)(e - s), 1.0f);
    *(f32x4*)(dst + (size_t)n * DIM + lane * 4) = acc0 * inv;
}

// Hop 2 only at batch nodes, fused with struct = (emb + out1 + out2)/3.
__global__ void k_gather2(const int* __restrict__ nidx, const int* __restrict__ offsets,
                          const int* __restrict__ sorted, const float* __restrict__ relw,
                          const float* __restrict__ out1, const float* __restrict__ emb,
                          float* __restrict__ structb) {
    int tid = threadIdx.x;
    int w = tid >> 6, lane = tid & 63;
    int b = blockIdx.x * 4 + w;          // grid = 1024 blocks, exact
    int n = nidx[b];
    int s = offsets[n], e = offsets[n + 1];
    f32x4 acc0 = (f32x4){0.f, 0.f, 0.f, 0.f};
    f32x4 acc1 = (f32x4){0.f, 0.f, 0.f, 0.f};
    f32x4 acc2 = (f32x4){0.f, 0.f, 0.f, 0.f};
    f32x4 acc3 = (f32x4){0.f, 0.f, 0.f, 0.f};
    int j = s;
    for (; j + 4 <= e; j += 4) {
        int p0 = sorted[j], p1 = sorted[j + 1], p2 = sorted[j + 2], p3 = sorted[j + 3];
        f32x4 v0 = *(const f32x4*)(out1 + (size_t)(p0 & 0xFFFF) * DIM + lane * 4);
        f32x4 v1 = *(const f32x4*)(out1 + (size_t)(p1 & 0xFFFF) * DIM + lane * 4);
        f32x4 v2 = *(const f32x4*)(out1 + (size_t)(p2 & 0xFFFF) * DIM + lane * 4);
        f32x4 v3 = *(const f32x4*)(out1 + (size_t)(p3 & 0xFFFF) * DIM + lane * 4);
        acc0 += v0 * *(const f32x4*)(relw + (p0 >> 16) * DIM + lane * 4);
        acc1 += v1 * *(const f32x4*)(relw + (p1 >> 16) * DIM + lane * 4);
        acc2 += v2 * *(const f32x4*)(relw + (p2 >> 16) * DIM + lane * 4);
        acc3 += v3 * *(const f32x4*)(relw + (p3 >> 16) * DIM + lane * 4);
    }
    for (; j < e; j++) {
        int p0 = sorted[j];
        f32x4 v0 = *(const f32x4*)(out1 + (size_t)(p0 & 0xFFFF) * DIM + lane * 4);
        acc0 += v0 * *(const f32x4*)(relw + (p0 >> 16) * DIM + lane * 4);
    }
    acc0 = (acc0 + acc1) + (acc2 + acc3);
    float inv = 1.0f / fmaxf((float)(e - s), 1.0f);
    f32x4 o2 = acc0 * inv;
    f32x4 e0 = *(const f32x4*)(emb + (size_t)n * DIM + lane * 4);
    f32x4 o1 = *(const f32x4*)(out1 + (size_t)n * DIM + lane * 4);
    *(f32x4*)(structb + (size_t)b * DIM + lane * 4) = (e0 + o1 + o2) * (1.0f / 3.0f);
}

// ---------------- BiLSTM: intra-wave 2-group software pipeline ----------------
// Block = 8 waves (512 thr), 2 groups x 16 samples, one dir. Grid (128,2)=256.
// Wave w owns cols [w*16,w*16+16) x 4 gates for BOTH groups (shared wreg).
// Groups live in separate __shared__ arrays (SA/SB) with ping-pong buffers:
// per iteration t:  [MFMA-B(t) || cell-A(t)+stage-A]  barrier
//                   [MFMA-A(t+1) || cell-B(t)+stage-B] barrier
// The MFMA and cell in each half are independent -> compiler interleaves; MFMA
// execution hides under cell VALU/trans. One barrier per group-step.
__launch_bounds__(512)
__global__ void k_lstm(const float* __restrict__ ts, const __bf16* __restrict__ w2frag,
                       const float* __restrict__ b_f, const float* __restrict__ b_b,
                       float* __restrict__ temporal) {
    int dir = blockIdx.y;
    int btile = blockIdx.x;    // 0..127
    int tid = threadIdx.x;
    int w = tid >> 6;          // wave 0..7
    int lane = tid & 63;
    int col = lane & 15, quad = lane >> 4;

    // [buf][row][k], rows 16, k: 0..63 = x, 64..191 = h, padded to 200 (16B-aligned rows)
    __shared__ __align__(16) __bf16 SA[2 * 16 * 200];
    __shared__ __align__(16) __bf16 SB[2 * 16 * 200];

    // zero h region of buf 0, both groups (h(-1) = 0)
    for (int i = tid; i < 2048; i += 512) {
        int m = i >> 7, k = i & 127;
        SA[m * 200 + 64 + k] = (__bf16)0.0f;
        SB[m * 200 + 64 + k] = (__bf16)0.0f;
    }

    const float* bias = dir ? b_b : b_f;
    float bv[4];
#pragma unroll
    for (int g = 0; g < 4; g++) bv[g] = bias[g * 128 + w * 16 + col];

    const __bf16* wbase = w2frag + (size_t)dir * 98304 + (size_t)w * 12288;
    bf16x8 wreg[24];
#pragma unroll
    for (int f = 0; f < 24; f++) {
        wreg[f] = *(const bf16x8*)(wbase + (f << 9) + lane * 8);
    }

    // x staging: 16 rows x 64 cols per group; thread -> (sm, sc)
    int sm = tid >> 5, sc = (tid & 31) * 2;
    const float* xbA = ts + ((size_t)(btile * 32 + sm) * SEQ) * INP + sc;
    const float* xbB = ts + ((size_t)(btile * 32 + 16 + sm) * SEQ) * INP + sc;
    int t0i = dir ? (SEQ - 1) : 0;
    int t1i = dir ? (SEQ - 2) : 1;
    {   // stage x(0) for both groups into buf 0
        f32x2 xa = *(const f32x2*)(xbA + (size_t)t0i * INP);
        f32x2 xb = *(const f32x2*)(xbB + (size_t)t0i * INP);
        bf16x2 va; va[0] = (__bf16)xa.x; va[1] = (__bf16)xa.y;
        bf16x2 vb; vb[0] = (__bf16)xb.x; vb[1] = (__bf16)xb.y;
        *(bf16x2*)&SA[sm * 200 + sc] = va;
        *(bf16x2*)&SB[sm * 200 + sc] = vb;
    }
    f32x2 xpreA = *(const f32x2*)(xbA + (size_t)t1i * INP);
    f32x2 xpreB = *(const f32x2*)(xbB + (size_t)t1i * INP);

    f32x4 cA = (f32x4){0.f, 0.f, 0.f, 0.f}, hsA = cA;
    f32x4 cB = cA, hsB = cA;
    f32x4 accA[4], accB[4];
    int hwr = quad * 4 * 200 + 64 + w * 16 + col;   // h write base (row=quad*4, +r*200)
    int ard = col * 200 + quad * 8;                  // A-frag read base
    __syncthreads();

    // prologue MFMA-A(0) from SA buf 0
#pragma unroll
    for (int g = 0; g < 4; g++) accA[g] = (f32x4){bv[g], bv[g], bv[g], bv[g]};
#pragma unroll
    for (int kc = 0; kc < 6; kc++) {
        bf16x8 a0 = *(const bf16x8*)&SA[ard + kc * 32];
#pragma unroll
        for (int g = 0; g < 4; g++)
            accA[g] = __builtin_amdgcn_mfma_f32_16x16x32_bf16(a0, wreg[g * 6 + kc], accA[g], 0, 0, 0);
    }

    for (int t = 0; t < SEQ; t++) {
        int cb = (t & 1) * 3200;         // current buf offset
        int nb = ((t + 1) & 1) * 3200;   // next buf offset

        // ---- first half: MFMA-B(t) (reads SB[cb]) || cell-A(t) (writes SA[nb]) ----
#pragma unroll
        for (int g = 0; g < 4; g++) accB[g] = (f32x4){bv[g], bv[g], bv[g], bv[g]};
#pragma unroll
        for (int kc = 0; kc < 6; kc++) {
            bf16x8 a0 = *(const bf16x8*)&SB[cb + ard + kc * 32];
#pragma unroll
            for (int g = 0; g < 4; g++)
                accB[g] = __builtin_amdgcn_mfma_f32_16x16x32_bf16(a0, wreg[g * 6 + kc], accB[g], 0, 0, 0);
        }
#pragma unroll
        for (int r = 0; r < 4; r++) {
            float c = sigmoidf_(accA[1][r]) * cA[r] + sigmoidf_(accA[0][r]) * tanhf_(accA[2][r]);
            float h = sigmoidf_(accA[3][r]) * tanhf_(c);
            cA[r] = c;
            hsA[r] += h;
            SA[nb + hwr + r * 200] = (__bf16)h;
        }
        if (t + 1 < SEQ) {
            bf16x2 v; v[0] = (__bf16)xpreA.x; v[1] = (__bf16)xpreA.y;
            *(bf16x2*)&SA[nb + sm * 200 + sc] = v;
            if (t + 2 < SEQ) {
                int ti = dir ? (SEQ - 3 - t) : (t + 2);
                xpreA = *(const f32x2*)(xbA + (size_t)ti * INP);
            }
        }
        __syncthreads();

        // ---- second half: MFMA-A(t+1) (reads SA[nb]) || cell-B(t) (writes SB[nb]) ----
        if (t + 1 < SEQ) {
#pragma unroll
            for (int g = 0; g < 4; g++) accA[g] = (f32x4){bv[g], bv[g], bv[g], bv[g]};
#pragma unroll
            for (int kc = 0; kc < 6; kc++) {
                bf16x8 a0 = *(const bf16x8*)&SA[nb + ard + kc * 32];
#pragma unroll
                for (int g = 0; g < 4; g++)
                    accA[g] = __builtin_amdgcn_mfma_f32_16x16x32_bf16(a0, wreg[g * 6 + kc], accA[g], 0, 0, 0);
            }
        }
#pragma unroll
        for (int r = 0; r < 4; r++) {
            float c = sigmoidf_(accB[1][r]) * cB[r] + sigmoidf_(accB[0][r]) * tanhf_(accB[2][r]);
            float h = sigmoidf_(accB[3][r]) * tanhf_(c);
            cB[r] = c;
            hsB[r] += h;
            SB[nb + hwr + r * 200] = (__bf16)h;
        }
        if (t + 1 < SEQ) {
            bf16x2 v; v[0] = (__bf16)xpreB.x; v[1] = (__bf16)xpreB.y;
            *(bf16x2*)&SB[nb + sm * 200 + sc] = v;
            if (t + 2 < SEQ) {
                int ti = dir ? (SEQ - 3 - t) : (t + 2);
                xpreB = *(const f32x2*)(xbB + (size_t)ti * INP);
            }
        }
        __syncthreads();
    }

    // temporal[b][dir*128 + j] = mean over t of h
#pragma unroll
    for (int r = 0; r < 4; r++) {
        int j = w * 16 + col;
        int bA = btile * 32 + quad * 4 + r;
        int bB = bA + 16;
        temporal[(size_t)bA * 256 + dir * 128 + j] = hsA[r] * (1.0f / SEQ);
        temporal[(size_t)bB * 256 + dir * 128 + j] = hsB[r] * (1.0f / SEQ);
    }
}

// ---------------- Head (fused gate+risk1+final) ----------------

// One block = 16 samples, 4 waves. Wave w owns out cols [w*64, w*64+64).
__launch_bounds__(256)
__global__ void k_head(const float* __restrict__ structb, const float* __restrict__ temporal,
                       const __bf16* __restrict__ gwp, const __bf16* __restrict__ w1p,
                       const float* __restrict__ gate_b, const float* __restrict__ risk_b1,
                       const float* __restrict__ w2s, float* __restrict__ out) {
    int bt = blockIdx.x;
    int tid = threadIdx.x;
    int w = tid >> 6, lane = tid & 63;
    int col = lane & 15, quad = lane >> 4;

    __shared__ __align__(16) __bf16 cat[16][520];
    __shared__ __align__(16) __bf16 mbuf[16][264];
    __shared__ float sacc[16];

    for (int i = tid; i < 16 * 512; i += 256) {
        int m = i >> 9, k = i & 511;
        int b = bt * 16 + m;
        float v = (k < 256) ? structb[(size_t)b * 256 + k]
                            : temporal[(size_t)b * 256 + (k - 256)];
        cat[m][k] = (__bf16)v;
    }
    if (tid < 16) sacc[tid] = 0.0f;
    __syncthreads();

    // gate GEMM: K=512 (16 kc-chunks)
    f32x4 acc[4];
#pragma unroll
    for (int ct = 0; ct < 4; ct++) {
        float b = gate_b[w * 64 + ct * 16 + col];
        acc[ct] = (f32x4){b, b, b, b};
    }
#pragma unroll
    for (int kc = 0; kc < 16; kc++) {
        bf16x8 a = *(const bf16x8*)&cat[col][kc * 32 + quad * 8];
#pragma unroll
        for (int ct = 0; ct < 4; ct++) {
            bf16x8 bf = *(const bf16x8*)(gwp + (((w * 4 + ct) * 16 + kc) << 9) + lane * 8);
            acc[ct] = __builtin_amdgcn_mfma_f32_16x16x32_bf16(a, bf, acc[ct], 0, 0, 0);
        }
    }
    // sigmoid + merge -> mbuf
#pragma unroll
    for (int ct = 0; ct < 4; ct++) {
        int n = w * 64 + ct * 16 + col;
#pragma unroll
        for (int r = 0; r < 4; r++) {
            int m = quad * 4 + r;
            int b = bt * 16 + m;
            float g = sigmoidf_(acc[ct][r]);
            float s = structb[(size_t)b * 256 + n];
            float tm = temporal[(size_t)b * 256 + n];
            mbuf[m][n] = (__bf16)(g * s + (1.0f - g) * tm);
        }
    }
    __syncthreads();

    // risk1 GEMM: K=256 (8 kc-chunks)
    f32x4 acc2[4];
#pragma unroll
    for (int ct = 0; ct < 4; ct++) {
        float b = risk_b1[w * 64 + ct * 16 + col];
        acc2[ct] = (f32x4){b, b, b, b};
    }
#pragma unroll
    for (int kc = 0; kc < 8; kc++) {
        bf16x8 a = *(const bf16x8*)&mbuf[col][kc * 32 + quad * 8];
#pragma unroll
        for (int ct = 0; ct < 4; ct++) {
            bf16x8 bf = *(const bf16x8*)(w1p + (((w * 4 + ct) * 8 + kc) << 9) + lane * 8);
            acc2[ct] = __builtin_amdgcn_mfma_f32_16x16x32_bf16(a, bf, acc2[ct], 0, 0, 0);
        }
    }
    // tanh + dot with w2s, reduce across the 16 lanes of each quad-group
    float part[4] = {0.f, 0.f, 0.f, 0.f};
#pragma unroll
    for (int ct = 0; ct < 4; ct++) {
        int n = w * 64 + ct * 16 + col;
        float wv = w2s[n];
#pragma unroll
        for (int r = 0; r < 4; r++) {
            part[r] += tanhf_(acc2[ct][r]) * wv;
        }
    }
#pragma unroll
    for (int off = 1; off < 16; off <<= 1) {
#pragma unroll
        for (int r = 0; r < 4; r++) part[r] += __shfl_xor(part[r], off, 64);
    }
    if (col == 0) {
#pragma unroll
        for (int r = 0; r < 4; r++) atomicAdd(&sacc[quad * 4 + r], part[r]);
    }
    __syncthreads();
    if (tid < 16) out[bt * 16 + tid] = sigmoidf_(sacc[tid] + w2s[256]);
}

// ---------------- launch ----------------

extern "C" void kernel_launch(void* const* d_in, const int* in_sizes, int n_in,
                              void* d_out, int out_size, void* d_ws, size_t ws_size,
                              hipStream_t stream) {
    const float* ts       = (const float*)d_in[0];
    const float* node_emb = (const float*)d_in[1];
    const float* rel_w    = (const float*)d_in[2];
    const float* gate_W   = (const float*)d_in[3];
    const float* gate_b   = (const float*)d_in[4];
    const float* risk_W1  = (const float*)d_in[5];
    const float* risk_b1  = (const float*)d_in[6];
    const float* risk_W2  = (const float*)d_in[7];
    const float* risk_b2  = (const float*)d_in[8];
    const float* Wih_f    = (const float*)d_in[9];
    const float* Whh_f    = (const float*)d_in[10];
    const float* b_f      = (const float*)d_in[11];
    const float* Wih_b    = (const float*)d_in[12];
    const float* Whh_b    = (const float*)d_in[13];
    const float* b_b      = (const float*)d_in[14];
    const int* edge_index = (const int*)d_in[15];
    const int* edge_type  = (const int*)d_in[16];
    const int* node_idx   = (const int*)d_in[17];
    const int* head = edge_index;
    const int* tail = edge_index + N_EDGES;
    float* out = (float*)d_out;

    char* ws = (char*)d_ws;
    const size_t o_deg      = 0;                            // 50000 int
    const size_t o_flagbuf  = 200704;                       // 50176 B (12544 ints)
    const size_t o_bsum     = o_flagbuf + 50176;            // 196 int -> pad 1024
    const size_t o_boff     = o_bsum + 1024;                // 256 int
    const size_t o_offsets  = o_boff + 1024;                // 50001 int -> pad 200960
    const size_t o_cursor   = o_offsets + 200960;           // 50000 int
    const size_t o_sorted   = o_cursor + 200704;            // 300000 int
    const size_t o_out1     = o_sorted + 1200128;           // 51,200,000 B
    const size_t o_temporal = o_out1 + 51200000;            // 4 MB
    const size_t o_struct   = o_temporal + 4194304;         // 4 MB
    const size_t o_gwp      = o_struct + 4194304;           // 262144 B
    const size_t o_w1p      = o_gwp + 262144;               // 131072 B
    const size_t o_w2s      = o_w1p + 131072;               // 257 f -> pad 2048
    const size_t o_w2frag   = o_w2s + 2048;                 // 393216 B

    int*    deg      = (int*)(ws + o_deg);
    char*   flag     = (char*)(ws + o_flagbuf);
    int*    flagi    = (int*)(ws + o_flagbuf);
    int*    bsum     = (int*)(ws + o_bsum);
    int*    boff     = (int*)(ws + o_boff);
    int*    offsets  = (int*)(ws + o_offsets);
    int*    cursor   = (int*)(ws + o_cursor);
    int*    sorted   = (int*)(ws + o_sorted);
    float*  out1     = (float*)(ws + o_out1);
    float*  temporal = (float*)(ws + o_temporal);
    float*  structb  = (float*)(ws + o_struct);
    __bf16* gwp      = (__bf16*)(ws + o_gwp);
    __bf16* w1p      = (__bf16*)(ws + o_w1p);
    float*  w2s      = (float*)(ws + o_w2s);
    __bf16* w2frag   = (__bf16*)(ws + o_w2frag);

    // fused prep: weight packs + w2 colsum + zero deg/flag (no memsets)
    k_prep<<<1782, 256, 0, stream>>>(Wih_f, Whh_f, Wih_b, Whh_b, gate_W, risk_W1,
                                     risk_W2, risk_b2, w2frag, gwp, w1p, w2s, deg, flagi);
    // sort
    k_hist<<<(N_EDGES + 255) / 256, 256, 0, stream>>>(head, deg);
    k_bsum<<<SCAN_BLOCKS, 256, 0, stream>>>(deg, bsum);
    k_scanb<<<1, 256, 0, stream>>>(bsum, boff);
    k_scan2<<<SCAN_BLOCKS, 256, 0, stream>>>(deg, boff, offsets, cursor);
    k_place<<<(N_EDGES + 255) / 256, 256, 0, stream>>>(head, tail, edge_type, cursor, sorted);
    k_flag<<<BATCH / 256, 256, 0, stream>>>(node_idx, offsets, sorted, flag);
    // main chain
    k_gather<<<(N_NODES + 3) / 4, 256, 0, stream>>>(offsets, sorted, rel_w, node_emb, flag, out1);
    k_lstm<<<dim3(BATCH / 32, 2), 512, 0, stream>>>(ts, w2frag, b_f, b_b, temporal);
    k_gather2<<<BATCH / 4, 256, 0, stream>>>(node_idx, offsets, sorted, rel_w, out1, node_emb, structb);
    k_head<<<BATCH / 16, 256, 0, stream>>>(structb, temporal, gwp, w1p, gate_b, risk_b1, w2s, out);
}